// Round 7
// baseline (1499.269 us; speedup 1.0000x reference)
//
#include <hip/hip_runtime.h>
#include <stdint.h>

// Problem: B=64, T=128, F=1024, H=1024. x:[64,128,1024] f32, W:[2048,4096] f32, b:[4096] f32.
// out:[64,128,1024] f32.
#define BATCH 64
#define TSEQ  128
#define FDIM  1024
#define HDIM  1024
#define GDIM  4096              // 4H
#define MROWS 8192              // BATCH*TSEQ
#define NB    128               // persistent blocks in recurrent phase (co-resident on 256 CUs)

typedef short bf16x8 __attribute__((ext_vector_type(8)));   // 8 bf16 in 4 VGPRs
typedef float f32x4  __attribute__((ext_vector_type(4)));

__device__ __forceinline__ unsigned short f2bf(float f) {
    union { float f; uint32_t u; } v; v.f = f;
    uint32_t u = v.u;
    return (unsigned short)((u + 0x7FFFu + ((u >> 16) & 1u)) >> 16);  // RNE
}
__device__ __forceinline__ float bf2f(unsigned short h) {
    union { uint32_t u; float f; } v; v.u = ((uint32_t)h) << 16; return v.f;
}
__device__ __forceinline__ float sigmoidf_(float x) { return 1.f / (1.f + __expf(-x)); }
__device__ __forceinline__ float tanhf_(float x)    { return 2.f / (1.f + __expf(-2.f * x)) - 1.f; }

union SP { short s[8]; int4 v; };
union UU { int4 i; bf16x8 v; };

// L2-bypass 8B store (relaxed agent atomic -> global_store_dwordx2 sc0 sc1, lands at IF).
__device__ __forceinline__ void st64cc(void* p, unsigned long long v) {
    __hip_atomic_store((unsigned long long*)p, v, __ATOMIC_RELAXED, __HIP_MEMORY_SCOPE_AGENT);
}
// L2-bypass 4B store (flag signal).
__device__ __forceinline__ void st32cc(void* p, uint32_t v) {
    __hip_atomic_store((uint32_t*)p, v, __ATOMIC_RELAXED, __HIP_MEMORY_SCOPE_AGENT);
}

// ---------------- init: zero flags + h slot 0 ----------------
__global__ void k_init(uint32_t* p, int nwords) {
    int i = blockIdx.x * blockDim.x + threadIdx.x;
    int s = gridDim.x * blockDim.x;
    for (; i < nwords; i += s) p[i] = 0;
}

// ---------------- W fp32 [2048][4096] -> WxT hi/lo bf16 [4096][1024], WhT bf16 [4096][1024] ----
__global__ void k_tw(const float* __restrict__ W,
                     unsigned short* __restrict__ wxth, unsigned short* __restrict__ wxtl,
                     unsigned short* __restrict__ wht) {
    __shared__ float tile[64 * 65];
    const int nb = blockIdx.x;      // 0..63  (n tiles)
    const int kb = blockIdx.y;      // 0..31  (k tiles over 2048)
    const int t  = threadIdx.x;
    const int col = t & 63, rg = t >> 6;
#pragma unroll
    for (int i = 0; i < 16; i++) {
        int row = rg * 16 + i;
        tile[row * 65 + col] = W[(size_t)(kb * 64 + row) * 4096 + nb * 64 + col];
    }
    __syncthreads();
    if (kb < 16) {
        const int kbase = kb * 64;
#pragma unroll
        for (int i = 0; i < 16; i++) {
            int rp = rg * 16 + i;                      // n index within tile
            float v = tile[col * 65 + rp];             // = W[kb*64+col][nb*64+rp]
            unsigned short h = f2bf(v);
            size_t idx = (size_t)(nb * 64 + rp) * 1024 + kbase + col;
            wxth[idx] = h;
            wxtl[idx] = f2bf(v - bf2f(h));
        }
    } else {
        const int kbase = (kb - 16) * 64;
#pragma unroll
        for (int i = 0; i < 16; i++) {
            int rp = rg * 16 + i;
            float v = tile[col * 65 + rp];
            wht[(size_t)(nb * 64 + rp) * 1024 + kbase + col] = f2bf(v);
        }
    }
}

// ---------------- GEMM1: xz_f32[8192][4096] = x[8192][1024] @ Wx, split-bf16 (3-MFMA) ---------
__global__ __launch_bounds__(256) void k_gemm1(const float* __restrict__ Xf,
                                               const unsigned short* __restrict__ WxTh,
                                               const unsigned short* __restrict__ WxTl,
                                               float* __restrict__ xz) {
    __shared__ short Ash[128 * 40];   // stride 40 elems (80B) -> 2-way banks (free)
    __shared__ short Asl[128 * 40];
    __shared__ short Bsh[128 * 40];
    __shared__ short Bsl[128 * 40];
    const int n0 = blockIdx.x * 128;
    const int m0 = blockIdx.y * 128;
    const int t = threadIdx.x;
    const int wave = t >> 6, lane = t & 63;
    const int wm = wave >> 1, wn = wave & 1;
    const int q = lane >> 4, cl = lane & 15;
    const int row_a = t >> 2;            // 0..63
    const int kc = (t & 3) * 8;          // 8-elem chunk within the 32-elem k-slab

    f32x4 acc[4][4];
#pragma unroll
    for (int i = 0; i < 4; i++)
#pragma unroll
        for (int j = 0; j < 4; j++) acc[i][j] = (f32x4){0.f, 0.f, 0.f, 0.f};

    for (int kb = 0; kb < 32; kb++) {
        const int k0 = kb * 32;
        float va0[8], va1[8];
        {
            const float* p0 = Xf + (size_t)(m0 + row_a) * 1024 + k0 + kc;
            const float* p1 = Xf + (size_t)(m0 + 64 + row_a) * 1024 + k0 + kc;
            *(float4*)(va0)     = *(const float4*)(p0);
            *(float4*)(va0 + 4) = *(const float4*)(p0 + 4);
            *(float4*)(va1)     = *(const float4*)(p1);
            *(float4*)(va1 + 4) = *(const float4*)(p1 + 4);
        }
        int4 bh0 = *(const int4*)(WxTh + (size_t)(n0 + row_a)      * 1024 + k0 + kc);
        int4 bh1 = *(const int4*)(WxTh + (size_t)(n0 + 64 + row_a) * 1024 + k0 + kc);
        int4 bl0 = *(const int4*)(WxTl + (size_t)(n0 + row_a)      * 1024 + k0 + kc);
        int4 bl1 = *(const int4*)(WxTl + (size_t)(n0 + 64 + row_a) * 1024 + k0 + kc);
        __syncthreads();
        {
            SP h0, l0, h1, l1;
#pragma unroll
            for (int i = 0; i < 8; i++) {
                unsigned short h = f2bf(va0[i]);
                h0.s[i] = (short)h; l0.s[i] = (short)f2bf(va0[i] - bf2f(h));
                unsigned short g = f2bf(va1[i]);
                h1.s[i] = (short)g; l1.s[i] = (short)f2bf(va1[i] - bf2f(g));
            }
            *(int4*)(Ash + row_a * 40 + kc)        = h0.v;
            *(int4*)(Asl + row_a * 40 + kc)        = l0.v;
            *(int4*)(Ash + (64 + row_a) * 40 + kc) = h1.v;
            *(int4*)(Asl + (64 + row_a) * 40 + kc) = l1.v;
        }
        *(int4*)(Bsh + row_a * 40 + kc)        = bh0;
        *(int4*)(Bsh + (64 + row_a) * 40 + kc) = bh1;
        *(int4*)(Bsl + row_a * 40 + kc)        = bl0;
        *(int4*)(Bsl + (64 + row_a) * 40 + kc) = bl1;
        __syncthreads();
        bf16x8 ah[4], al[4], bh[4], bl[4];
#pragma unroll
        for (int i = 0; i < 4; i++) {
            ah[i] = *(const bf16x8*)(Ash + (wm * 64 + i * 16 + cl) * 40 + q * 8);
            al[i] = *(const bf16x8*)(Asl + (wm * 64 + i * 16 + cl) * 40 + q * 8);
        }
#pragma unroll
        for (int j = 0; j < 4; j++) {
            bh[j] = *(const bf16x8*)(Bsh + (wn * 64 + j * 16 + cl) * 40 + q * 8);
            bl[j] = *(const bf16x8*)(Bsl + (wn * 64 + j * 16 + cl) * 40 + q * 8);
        }
#pragma unroll
        for (int i = 0; i < 4; i++)
#pragma unroll
            for (int j = 0; j < 4; j++) {
                acc[i][j] = __builtin_amdgcn_mfma_f32_16x16x32_bf16(ah[i], bh[j], acc[i][j], 0, 0, 0);
                acc[i][j] = __builtin_amdgcn_mfma_f32_16x16x32_bf16(al[i], bh[j], acc[i][j], 0, 0, 0);
                acc[i][j] = __builtin_amdgcn_mfma_f32_16x16x32_bf16(ah[i], bl[j], acc[i][j], 0, 0, 0);
            }
    }
    // epilogue: C/D layout col=lane&15, row=q*4+reg; write fp32
#pragma unroll
    for (int i = 0; i < 4; i++) {
#pragma unroll
        for (int j = 0; j < 4; j++) {
            int gm = m0 + wm * 64 + i * 16 + q * 4;
            int gn = n0 + wn * 64 + j * 16 + cl;
#pragma unroll
            for (int r = 0; r < 4; r++)
                xz[(size_t)(gm + r) * 4096 + gn] = acc[i][j][r];
        }
    }
}

// ---------------- persistent recurrent kernel ----------------
// NB=128 blocks x 256 thr (4 waves, 1/SIMD). Block owns 8 h-cols -> 32 gate cols
// [i(8) j(8) | f(8) o(8)]. B (Wh slice) entirely in 256 VGPRs (round-5, verified).
// h exchange: ROTATING buffer (write-once addresses); producers bypass-store to IF,
// consumers normal cached loads. Distributed write-once flags.
// Sync-path restructure (round-6 design, store fixed to 2 x 8B atomic-bypass):
//  - wave0 = storer/signaler: reads all 64 rows from hs, 128 x 8B bypass stores,
//    WAVE-LOCAL s_waitcnt vmcnt(0), then flag. Full-block drain barrier deleted;
//    waves 1-3 overlap the drain with out-stores + next prefetch.
//  - wave1 = poller (decoupled from storer so last step's drain never delays poll
//    start), 2-deep pipelined poll loads (halve detect granularity).
__global__ __launch_bounds__(256, 1) void k_rnn(const float* __restrict__ xz,
                                                const unsigned short* __restrict__ WhT,
                                                const float* __restrict__ bias,
                                                unsigned short* hrot,       // 129 x [64][1024] bf16
                                                int* flags,                 // TSEQ x NB ints, write-once
                                                float* __restrict__ out) {
    __shared__ short hs[64 * 8];        // h transpose staging, 1 KB (only LDS)
    const int t = threadIdx.x;
    const int blk = blockIdx.x;
    // XCD-grouped columns: blocks blk&7==x own cols [x*128, x*128+128)
    const int n0 = (((blk & 7) << 4) | (blk >> 3)) * 8;
    const int wave = t >> 6, lane = t & 63;
    const int q = lane >> 4, cl = lane & 15;
    const int m = wave * 16 + cl;       // A-fragment row (batch)

    const int cc = cl & 7;
    const bool act = (cl < 8);
    float bi = 0.f, bj = 0.f, bfv = 0.f, bo = 0.f;
    if (act) {
        bi  = bias[n0 + cc];
        bj  = bias[1024 + n0 + cc];
        bfv = bias[2048 + n0 + cc];
        bo  = bias[3072 + n0 + cc];
    }

    // B preload (round-5, verified): lane (q,cl) holds for every k-step kb:
    //   B0[kb] = WhT[(cl>>3)*1024   + n0 + (cl&7)][kb*32+q*8 .. +8]   (gates i,j)
    //   B1[kb] = WhT[(2+(cl>>3))*1024 + n0 + (cl&7)][kb*32+q*8 .. +8] (gates f,o)
    bf16x8 B0[32], B1[32];
    {
        const unsigned short* bsrc0 =
            WhT + (size_t)((cl >> 3) * 1024 + n0 + (cl & 7)) * 1024 + q * 8;
        const unsigned short* bsrc1 =
            WhT + (size_t)((2 + (cl >> 3)) * 1024 + n0 + (cl & 7)) * 1024 + q * 8;
#pragma unroll
        for (int kb = 0; kb < 32; kb++) {
            UU u0, u1;
            u0.i = *(const int4*)(bsrc0 + kb * 32);
            u1.i = *(const int4*)(bsrc1 + kb * 32);
            B0[kb] = u0.v;
            B1[kb] = u1.v;
        }
    }

    float c[4] = {0.f, 0.f, 0.f, 0.f};
    // wave1 poll: lane covers flag words 2*lane, 2*lane+1; own flag OR'd in locally.
    const unsigned long long selfmask =
        (lane == (blk >> 1)) ? ((blk & 1) ? (1ULL << 32) : 1ULL) : 0ULL;

    for (int tt = 0; tt < TSEQ; tt++) {
        // prefetch xz for this step (independent of other blocks' h) — ISSUE BEFORE the spin
        float pxi[4], pxj[4], pxf[4], pxo[4];
        if (act) {
#pragma unroll
            for (int r = 0; r < 4; r++) {
                int m2 = wave * 16 + q * 4 + r;
                const float* xp = xz + (size_t)(m2 * 128 + tt) * 4096 + n0 + cc;
                pxi[r] = xp[0];
                pxj[r] = xp[1024];
                pxf[r] = xp[2048];
                pxo[r] = xp[3072];
            }
        }
        __builtin_amdgcn_sched_barrier(0);   // pin: prefetch issued before poll
        if (tt > 0) {
            if (wave == 1) {
                const unsigned long long* fp =
                    (const unsigned long long*)flags + (size_t)(tt - 1) * 64 + lane;
                bool okv;
                do {
                    unsigned long long v1 = __hip_atomic_load(fp, __ATOMIC_RELAXED,
                                                              __HIP_MEMORY_SCOPE_AGENT);
                    unsigned long long v2 = __hip_atomic_load(fp, __ATOMIC_RELAXED,
                                                              __HIP_MEMORY_SCOPE_AGENT);
                    okv = ((v1 | selfmask) == 0x0000000100000001ULL) ||
                          ((v2 | selfmask) == 0x0000000100000001ULL);
                } while (!__all(okv));
            }
            __syncthreads();   // barrierP: broadcast "all flags(tt-1) set"
        }
        // burst-load the FULL h row-slice (32 x int4 = 128 VGPRs), all in flight at once.
        // Addresses write-once => normal cached loads safe.
        const char* ab = (const char*)hrot + (size_t)tt * 131072 + (size_t)m * 2048 + q * 16;
        UU aa[32];
#pragma unroll
        for (int kb = 0; kb < 32; kb++) aa[kb].i = *(const int4*)(ab + kb * 64);
        __builtin_amdgcn_sched_barrier(0);   // pin: burst stays a burst

        f32x4 acc0a = (f32x4){0.f, 0.f, 0.f, 0.f};
        f32x4 acc0b = (f32x4){0.f, 0.f, 0.f, 0.f};
        f32x4 acc1a = (f32x4){0.f, 0.f, 0.f, 0.f};
        f32x4 acc1b = (f32x4){0.f, 0.f, 0.f, 0.f};
#pragma unroll
        for (int kb = 0; kb < 32; kb += 2) {
            acc0a = __builtin_amdgcn_mfma_f32_16x16x32_bf16(aa[kb].v,     B0[kb],     acc0a, 0, 0, 0);
            acc1a = __builtin_amdgcn_mfma_f32_16x16x32_bf16(aa[kb].v,     B1[kb],     acc1a, 0, 0, 0);
            acc0b = __builtin_amdgcn_mfma_f32_16x16x32_bf16(aa[kb + 1].v, B0[kb + 1], acc0b, 0, 0, 0);
            acc1b = __builtin_amdgcn_mfma_f32_16x16x32_bf16(aa[kb + 1].v, B1[kb + 1], acc1b, 0, 0, 0);
        }
        f32x4 acc0 = acc0a + acc0b;
        f32x4 acc1 = acc1a + acc1b;
        // gate math: lane (q,cl<8) row-group q*4+r, col cc; zj/zo live in lane^8
        float zi[4], zj[4], zf[4], zo[4];
#pragma unroll
        for (int r = 0; r < 4; r++) {
            float a0 = acc0[r], a1 = acc1[r];
            float a0x = __shfl_xor(a0, 8);
            float a1x = __shfl_xor(a1, 8);
            zi[r] = a0; zj[r] = a0x; zf[r] = a1; zo[r] = a1x;
        }
        float hv4[4];
        if (act) {
#pragma unroll
            for (int r = 0; r < 4; r++) {
                float vi = zi[r] + pxi[r] + bi;
                float vj = zj[r] + pxj[r] + bj;
                float vf = zf[r] + pxf[r] + bfv + 1.0f;    // forget bias
                float vo = zo[r] + pxo[r] + bo;
                float cn = c[r] * sigmoidf_(vf) + sigmoidf_(vi) * tanhf_(vj);
                c[r] = cn;
                float h = tanhf_(cn) * sigmoidf_(vo);
                hv4[r] = h;
                hs[(wave * 16 + q * 4 + r) * 8 + cc] = (short)f2bf(h);
            }
        }
        __syncthreads();   // barrierH: hs complete
        if (wave == 0) {
            // lane = row 0..63: 16B per row as 2 x 8B bypass stores (this block's 8 cols)
            unsigned long long h0 = *(const unsigned long long*)(hs + lane * 8);
            unsigned long long h1 = *(const unsigned long long*)(hs + lane * 8 + 4);
            char* dst = (char*)hrot + (size_t)(tt + 1) * 131072 + (size_t)lane * 2048 + n0 * 2;
            st64cc(dst, h0);
            st64cc(dst + 8, h1);
            asm volatile("s_waitcnt vmcnt(0)" ::: "memory");   // wave-local drain: h at IF
            __builtin_amdgcn_sched_barrier(0);
            if (lane == 0) st32cc(flags + (size_t)tt * NB + blk, 1u);
        }
        // out stores AFTER barrierH / signal — off the drain critical path
        if (act) {
#pragma unroll
            for (int r = 0; r < 4; r++) {
                int m2 = wave * 16 + q * 4 + r;
                out[(size_t)(m2 * 128 + tt) * 1024 + n0 + cc] = hv4[r];
            }
        }
    }
}

// ---------------- launch ----------------
extern "C" void kernel_launch(void* const* d_in, const int* in_sizes, int n_in,
                              void* d_out, int out_size, void* d_ws, size_t ws_size,
                              hipStream_t stream) {
    const float* x = (const float*)d_in[0];
    const float* W = (const float*)d_in[1];
    const float* b = (const float*)d_in[2];
    float* out = (float*)d_out;
    char* ws = (char*)d_ws;

    // workspace layout (bytes):
    unsigned short* WXTH = (unsigned short*)(ws);                              // 8 MB
    unsigned short* WXTL = (unsigned short*)(ws + (size_t)8  * 1024 * 1024);   // 8 MB
    unsigned short* WHT  = (unsigned short*)(ws + (size_t)16 * 1024 * 1024);   // 8 MB
    float*          XZ   = (float*)         (ws + (size_t)24 * 1024 * 1024);   // 128 MB fp32
    int*            FLAGS= (int*)           (ws + (size_t)152 * 1024 * 1024);  // 64 KB (TSEQ*NB)
    unsigned short* HROT = (unsigned short*)(ws + (size_t)152 * 1024 * 1024 + 65536); // 129*128KB

    // zero FLAGS (64 KB) + HROT slot 0 (128 KB) = 196608 B = 49152 words
    k_init<<<256, 256, 0, stream>>>((uint32_t*)FLAGS, 49152);
    dim3 gtw(64, 32);
    k_tw<<<gtw, 256, 0, stream>>>(W, WXTH, WXTL, WHT);
    dim3 gg(32, 64);   // x: N/128, y: M/128
    k_gemm1<<<gg, 256, 0, stream>>>(x, WXTH, WXTL, XZ);
    k_rnn<<<NB, 256, 0, stream>>>(XZ, WHT, b, HROT, FLAGS, out);
}

// Round 8
// 1045.373 us; speedup vs baseline: 1.4342x; 1.4342x over previous
//
#include <hip/hip_runtime.h>
#include <stdint.h>

// Problem: B=64, T=128, F=1024, H=1024. x:[64,128,1024] f32, W:[2048,4096] f32, b:[4096] f32.
// out:[64,128,1024] f32.
#define BATCH 64
#define TSEQ  128
#define FDIM  1024
#define HDIM  1024
#define GDIM  4096              // 4H
#define MROWS 8192              // BATCH*TSEQ
#define NB    128               // persistent blocks in recurrent phase (co-resident on 256 CUs)

typedef short bf16x8 __attribute__((ext_vector_type(8)));   // 8 bf16 in 4 VGPRs
typedef float f32x4  __attribute__((ext_vector_type(4)));

__device__ __forceinline__ unsigned short f2bf(float f) {
    union { float f; uint32_t u; } v; v.f = f;
    uint32_t u = v.u;
    return (unsigned short)((u + 0x7FFFu + ((u >> 16) & 1u)) >> 16);  // RNE
}
__device__ __forceinline__ float bf2f(unsigned short h) {
    union { uint32_t u; float f; } v; v.u = ((uint32_t)h) << 16; return v.f;
}
__device__ __forceinline__ float sigmoidf_(float x) { return 1.f / (1.f + __expf(-x)); }
__device__ __forceinline__ float tanhf_(float x)    { return 2.f / (1.f + __expf(-2.f * x)) - 1.f; }

union SP { short s[8]; int4 v; };
union UU { int4 i; bf16x8 v; };

// L2-bypass 8B store (relaxed agent atomic -> global_store_dwordx2 sc0 sc1, lands at IF).
__device__ __forceinline__ void st64cc(void* p, unsigned long long v) {
    __hip_atomic_store((unsigned long long*)p, v, __ATOMIC_RELAXED, __HIP_MEMORY_SCOPE_AGENT);
}
// L2-bypass 4B store (flag signal).
__device__ __forceinline__ void st32cc(void* p, uint32_t v) {
    __hip_atomic_store((uint32_t*)p, v, __ATOMIC_RELAXED, __HIP_MEMORY_SCOPE_AGENT);
}

// ---------------- init: zero flags + h slot 0 ----------------
__global__ void k_init(uint32_t* p, int nwords) {
    int i = blockIdx.x * blockDim.x + threadIdx.x;
    int s = gridDim.x * blockDim.x;
    for (; i < nwords; i += s) p[i] = 0;
}

// ---------------- x fp32 [8192][1024] -> Xh/Xl bf16 hi/lo (one-time; removes per-kb
// repack from gemm1's inner loop, where it was repeated by all 32 N-blocks) ----------
__global__ __launch_bounds__(256) void k_cx(const float* __restrict__ x,
                                            unsigned short* __restrict__ xh,
                                            unsigned short* __restrict__ xl) {
    const int i = (blockIdx.x * 256 + threadIdx.x) * 16;   // grid 2048 -> covers 8M elems
    float v[16];
    *(float4*)(v)      = *(const float4*)(x + i);
    *(float4*)(v + 4)  = *(const float4*)(x + i + 4);
    *(float4*)(v + 8)  = *(const float4*)(x + i + 8);
    *(float4*)(v + 12) = *(const float4*)(x + i + 12);
    SP h0, h1, l0, l1;
#pragma unroll
    for (int j = 0; j < 8; j++) {
        unsigned short h = f2bf(v[j]);
        h0.s[j] = (short)h; l0.s[j] = (short)f2bf(v[j] - bf2f(h));
        unsigned short g = f2bf(v[8 + j]);
        h1.s[j] = (short)g; l1.s[j] = (short)f2bf(v[8 + j] - bf2f(g));
    }
    *(int4*)(xh + i)     = h0.v;
    *(int4*)(xh + i + 8) = h1.v;
    *(int4*)(xl + i)     = l0.v;
    *(int4*)(xl + i + 8) = l1.v;
}

// ---------------- W fp32 [2048][4096] -> WxT hi/lo bf16 [4096][1024], WhT bf16 [4096][1024] ----
__global__ void k_tw(const float* __restrict__ W,
                     unsigned short* __restrict__ wxth, unsigned short* __restrict__ wxtl,
                     unsigned short* __restrict__ wht) {
    __shared__ float tile[64 * 65];
    const int nb = blockIdx.x;      // 0..63  (n tiles)
    const int kb = blockIdx.y;      // 0..31  (k tiles over 2048)
    const int t  = threadIdx.x;
    const int col = t & 63, rg = t >> 6;
#pragma unroll
    for (int i = 0; i < 16; i++) {
        int row = rg * 16 + i;
        tile[row * 65 + col] = W[(size_t)(kb * 64 + row) * 4096 + nb * 64 + col];
    }
    __syncthreads();
    if (kb < 16) {
        const int kbase = kb * 64;
#pragma unroll
        for (int i = 0; i < 16; i++) {
            int rp = rg * 16 + i;                      // n index within tile
            float v = tile[col * 65 + rp];             // = W[kb*64+col][nb*64+rp]
            unsigned short h = f2bf(v);
            size_t idx = (size_t)(nb * 64 + rp) * 1024 + kbase + col;
            wxth[idx] = h;
            wxtl[idx] = f2bf(v - bf2f(h));
        }
    } else {
        const int kbase = (kb - 16) * 64;
#pragma unroll
        for (int i = 0; i < 16; i++) {
            int rp = rg * 16 + i;
            float v = tile[col * 65 + rp];
            wht[(size_t)(nb * 64 + rp) * 1024 + kbase + col] = f2bf(v);
        }
    }
}

// ---------------- GEMM1: xz_f32[8192][4096] = x[8192][1024] @ Wx, split-bf16 (3-MFMA) ---------
// use_pre=1: A staged from precomputed Xh/Xl (int4 load -> LDS, zero VALU repack).
// use_pre=0: legacy in-loop fp32->hi/lo conversion (workspace too small for Xh/Xl).
__global__ __launch_bounds__(256) void k_gemm1(const float* __restrict__ Xf,
                                               const unsigned short* __restrict__ Xh,
                                               const unsigned short* __restrict__ Xl,
                                               const unsigned short* __restrict__ WxTh,
                                               const unsigned short* __restrict__ WxTl,
                                               float* __restrict__ xz, int use_pre) {
    __shared__ short Ash[128 * 40];   // stride 40 elems (80B) -> 2-way banks (free)
    __shared__ short Asl[128 * 40];
    __shared__ short Bsh[128 * 40];
    __shared__ short Bsl[128 * 40];
    const int n0 = blockIdx.x * 128;
    const int m0 = blockIdx.y * 128;
    const int t = threadIdx.x;
    const int wave = t >> 6, lane = t & 63;
    const int wm = wave >> 1, wn = wave & 1;
    const int q = lane >> 4, cl = lane & 15;
    const int row_a = t >> 2;            // 0..63
    const int kc = (t & 3) * 8;          // 8-elem chunk within the 32-elem k-slab

    f32x4 acc[4][4];
#pragma unroll
    for (int i = 0; i < 4; i++)
#pragma unroll
        for (int j = 0; j < 4; j++) acc[i][j] = (f32x4){0.f, 0.f, 0.f, 0.f};

    for (int kb = 0; kb < 32; kb++) {
        const int k0 = kb * 32;
        float va0[8], va1[8];
        int4 pah0, pal0, pah1, pal1;
        if (use_pre) {
            pah0 = *(const int4*)(Xh + (size_t)(m0 + row_a)      * 1024 + k0 + kc);
            pal0 = *(const int4*)(Xl + (size_t)(m0 + row_a)      * 1024 + k0 + kc);
            pah1 = *(const int4*)(Xh + (size_t)(m0 + 64 + row_a) * 1024 + k0 + kc);
            pal1 = *(const int4*)(Xl + (size_t)(m0 + 64 + row_a) * 1024 + k0 + kc);
        } else {
            const float* p0 = Xf + (size_t)(m0 + row_a) * 1024 + k0 + kc;
            const float* p1 = Xf + (size_t)(m0 + 64 + row_a) * 1024 + k0 + kc;
            *(float4*)(va0)     = *(const float4*)(p0);
            *(float4*)(va0 + 4) = *(const float4*)(p0 + 4);
            *(float4*)(va1)     = *(const float4*)(p1);
            *(float4*)(va1 + 4) = *(const float4*)(p1 + 4);
        }
        int4 bh0 = *(const int4*)(WxTh + (size_t)(n0 + row_a)      * 1024 + k0 + kc);
        int4 bh1 = *(const int4*)(WxTh + (size_t)(n0 + 64 + row_a) * 1024 + k0 + kc);
        int4 bl0 = *(const int4*)(WxTl + (size_t)(n0 + row_a)      * 1024 + k0 + kc);
        int4 bl1 = *(const int4*)(WxTl + (size_t)(n0 + 64 + row_a) * 1024 + k0 + kc);
        __syncthreads();
        if (use_pre) {
            *(int4*)(Ash + row_a * 40 + kc)        = pah0;
            *(int4*)(Asl + row_a * 40 + kc)        = pal0;
            *(int4*)(Ash + (64 + row_a) * 40 + kc) = pah1;
            *(int4*)(Asl + (64 + row_a) * 40 + kc) = pal1;
        } else {
            SP h0, l0, h1, l1;
#pragma unroll
            for (int i = 0; i < 8; i++) {
                unsigned short h = f2bf(va0[i]);
                h0.s[i] = (short)h; l0.s[i] = (short)f2bf(va0[i] - bf2f(h));
                unsigned short g = f2bf(va1[i]);
                h1.s[i] = (short)g; l1.s[i] = (short)f2bf(va1[i] - bf2f(g));
            }
            *(int4*)(Ash + row_a * 40 + kc)        = h0.v;
            *(int4*)(Asl + row_a * 40 + kc)        = l0.v;
            *(int4*)(Ash + (64 + row_a) * 40 + kc) = h1.v;
            *(int4*)(Asl + (64 + row_a) * 40 + kc) = l1.v;
        }
        *(int4*)(Bsh + row_a * 40 + kc)        = bh0;
        *(int4*)(Bsh + (64 + row_a) * 40 + kc) = bh1;
        *(int4*)(Bsl + row_a * 40 + kc)        = bl0;
        *(int4*)(Bsl + (64 + row_a) * 40 + kc) = bl1;
        __syncthreads();
        bf16x8 ah[4], al[4], bh[4], bl[4];
#pragma unroll
        for (int i = 0; i < 4; i++) {
            ah[i] = *(const bf16x8*)(Ash + (wm * 64 + i * 16 + cl) * 40 + q * 8);
            al[i] = *(const bf16x8*)(Asl + (wm * 64 + i * 16 + cl) * 40 + q * 8);
        }
#pragma unroll
        for (int j = 0; j < 4; j++) {
            bh[j] = *(const bf16x8*)(Bsh + (wn * 64 + j * 16 + cl) * 40 + q * 8);
            bl[j] = *(const bf16x8*)(Bsl + (wn * 64 + j * 16 + cl) * 40 + q * 8);
        }
#pragma unroll
        for (int i = 0; i < 4; i++)
#pragma unroll
            for (int j = 0; j < 4; j++) {
                acc[i][j] = __builtin_amdgcn_mfma_f32_16x16x32_bf16(ah[i], bh[j], acc[i][j], 0, 0, 0);
                acc[i][j] = __builtin_amdgcn_mfma_f32_16x16x32_bf16(al[i], bh[j], acc[i][j], 0, 0, 0);
                acc[i][j] = __builtin_amdgcn_mfma_f32_16x16x32_bf16(ah[i], bl[j], acc[i][j], 0, 0, 0);
            }
    }
    // epilogue: C/D layout col=lane&15, row=q*4+reg; write fp32
#pragma unroll
    for (int i = 0; i < 4; i++) {
#pragma unroll
        for (int j = 0; j < 4; j++) {
            int gm = m0 + wm * 64 + i * 16 + q * 4;
            int gn = n0 + wn * 64 + j * 16 + cl;
#pragma unroll
            for (int r = 0; r < 4; r++)
                xz[(size_t)(gm + r) * 4096 + gn] = acc[i][j][r];
        }
    }
}

// ---------------- persistent recurrent kernel (EXACT round-5 revert: 750 us best) ----------------
// NB=128 blocks x 256 thr (4 waves, 1/SIMD). Block owns 8 h-cols -> 32 gate cols
// [i(8) j(8) | f(8) o(8)]. B (Wh slice) entirely in 256 VGPRs.
// h exchange: ROTATING buffer (write-once addresses); producers bypass-store to IF,
// consumers normal cached loads. Distributed write-once flags, full-barrier poll.
__global__ __launch_bounds__(256, 1) void k_rnn(const float* __restrict__ xz,
                                                const unsigned short* __restrict__ WhT,
                                                const float* __restrict__ bias,
                                                unsigned short* hrot,       // 129 x [64][1024] bf16
                                                int* flags,                 // TSEQ x NB ints, write-once
                                                float* __restrict__ out) {
    __shared__ short hs[64 * 8];        // h transpose staging, 1 KB (only LDS left)
    const int t = threadIdx.x;
    const int blk = blockIdx.x;
    // XCD-grouped columns: blocks blk&7==x own cols [x*128, x*128+128)
    const int n0 = (((blk & 7) << 4) | (blk >> 3)) * 8;
    const int wave = t >> 6, lane = t & 63;
    const int q = lane >> 4, cl = lane & 15;
    const int m = wave * 16 + cl;       // A-fragment row (batch)

    const int cc = cl & 7;
    const bool act = (cl < 8);
    float bi = 0.f, bj = 0.f, bfv = 0.f, bo = 0.f;
    if (act) {
        bi  = bias[n0 + cc];
        bj  = bias[1024 + n0 + cc];
        bfv = bias[2048 + n0 + cc];
        bo  = bias[3072 + n0 + cc];
    }

    // B preload: lane (q,cl) holds, for every k-step kb:
    //   B0[kb] = WhT[(cl>>3)*1024   + n0 + (cl&7)][kb*32+q*8 .. +8]   (gates i,j)
    //   B1[kb] = WhT[(2+(cl>>3))*1024 + n0 + (cl&7)][kb*32+q*8 .. +8] (gates f,o)
    bf16x8 B0[32], B1[32];
    {
        const unsigned short* bsrc0 =
            WhT + (size_t)((cl >> 3) * 1024 + n0 + (cl & 7)) * 1024 + q * 8;
        const unsigned short* bsrc1 =
            WhT + (size_t)((2 + (cl >> 3)) * 1024 + n0 + (cl & 7)) * 1024 + q * 8;
#pragma unroll
        for (int kb = 0; kb < 32; kb++) {
            UU u0, u1;
            u0.i = *(const int4*)(bsrc0 + kb * 32);
            u1.i = *(const int4*)(bsrc1 + kb * 32);
            B0[kb] = u0.v;
            B1[kb] = u1.v;
        }
    }

    float c[4] = {0.f, 0.f, 0.f, 0.f};
    // wave-0..3 poll: lane l covers flag words 2l,2l+1; own flag OR'd in locally.
    const unsigned long long selfmask =
        ((t & 63) == (blk >> 1)) ? ((blk & 1) ? (1ULL << 32) : 1ULL) : 0ULL;

    for (int tt = 0; tt < TSEQ; tt++) {
        // prefetch xz for this step (independent of other blocks' h) — ISSUE BEFORE the spin
        float pxi[4], pxj[4], pxf[4], pxo[4];
        if (act) {
#pragma unroll
            for (int r = 0; r < 4; r++) {
                int m2 = wave * 16 + q * 4 + r;
                const float* xp = xz + (size_t)(m2 * 128 + tt) * 4096 + n0 + cc;
                pxi[r] = xp[0];
                pxj[r] = xp[1024];
                pxf[r] = xp[2048];
                pxo[r] = xp[3072];
            }
        }
        __builtin_amdgcn_sched_barrier(0);   // pin: prefetch issued before poll
        if (tt > 0) {
            if (t < 64) {
                const unsigned long long* fp =
                    (const unsigned long long*)flags + (size_t)(tt - 1) * 64 + t;
                unsigned long long v;
                do {
                    v = __hip_atomic_load(fp, __ATOMIC_RELAXED, __HIP_MEMORY_SCOPE_AGENT);
                } while (!__all((v | selfmask) == 0x0000000100000001ULL));
            }
            __syncthreads();
        }
        // burst-load the FULL h row-slice (32 x int4 = 128 VGPRs), all in flight at once.
        // Addresses write-once => normal cached loads safe.
        const char* ab = (const char*)hrot + (size_t)tt * 131072 + (size_t)m * 2048 + q * 16;
        UU aa[32];
#pragma unroll
        for (int kb = 0; kb < 32; kb++) aa[kb].i = *(const int4*)(ab + kb * 64);
        __builtin_amdgcn_sched_barrier(0);   // pin: burst stays a burst

        f32x4 acc0a = (f32x4){0.f, 0.f, 0.f, 0.f};
        f32x4 acc0b = (f32x4){0.f, 0.f, 0.f, 0.f};
        f32x4 acc1a = (f32x4){0.f, 0.f, 0.f, 0.f};
        f32x4 acc1b = (f32x4){0.f, 0.f, 0.f, 0.f};
#pragma unroll
        for (int kb = 0; kb < 32; kb += 2) {
            acc0a = __builtin_amdgcn_mfma_f32_16x16x32_bf16(aa[kb].v,     B0[kb],     acc0a, 0, 0, 0);
            acc1a = __builtin_amdgcn_mfma_f32_16x16x32_bf16(aa[kb].v,     B1[kb],     acc1a, 0, 0, 0);
            acc0b = __builtin_amdgcn_mfma_f32_16x16x32_bf16(aa[kb + 1].v, B0[kb + 1], acc0b, 0, 0, 0);
            acc1b = __builtin_amdgcn_mfma_f32_16x16x32_bf16(aa[kb + 1].v, B1[kb + 1], acc1b, 0, 0, 0);
        }
        f32x4 acc0 = acc0a + acc0b;
        f32x4 acc1 = acc1a + acc1b;
        // gate math: lane (q,cl<8) row-group q*4+r, col cc; zj/zo live in lane^8
        float zi[4], zj[4], zf[4], zo[4];
#pragma unroll
        for (int r = 0; r < 4; r++) {
            float a0 = acc0[r], a1 = acc1[r];
            float a0x = __shfl_xor(a0, 8);
            float a1x = __shfl_xor(a1, 8);
            zi[r] = a0; zj[r] = a0x; zf[r] = a1; zo[r] = a1x;
        }
        float hv4[4];
        if (act) {
#pragma unroll
            for (int r = 0; r < 4; r++) {
                float vi = zi[r] + pxi[r] + bi;
                float vj = zj[r] + pxj[r] + bj;
                float vf = zf[r] + pxf[r] + bfv + 1.0f;    // forget bias
                float vo = zo[r] + pxo[r] + bo;
                float cn = c[r] * sigmoidf_(vf) + sigmoidf_(vi) * tanhf_(vj);
                c[r] = cn;
                float h = tanhf_(cn) * sigmoidf_(vo);
                hv4[r] = h;
                hs[(wave * 16 + q * 4 + r) * 8 + cc] = (short)f2bf(h);
            }
        }
        __syncthreads();   // hs visible to all waves
        if (t < 128) {
            // row = t>>1 (0..63), half = t&1; 8B per store
            unsigned long long hv = *(const unsigned long long*)(hs + (t >> 1) * 8 + (t & 1) * 4);
            st64cc((char*)hrot + (size_t)(tt + 1) * 131072 + (size_t)(t >> 1) * 2048 + n0 * 2 + (t & 1) * 8, hv);
        }
        __syncthreads();   // vmcnt(0): h row-stores ACK'd at IF before signal
        if (t == 0) st32cc(flags + (size_t)tt * NB + blk, 1u);
        // out stores AFTER the signal — off the pre-signal drain critical path
        if (act) {
#pragma unroll
            for (int r = 0; r < 4; r++) {
                int m2 = wave * 16 + q * 4 + r;
                out[(size_t)(m2 * 128 + tt) * 1024 + n0 + cc] = hv4[r];
            }
        }
    }
}

// ---------------- launch ----------------
extern "C" void kernel_launch(void* const* d_in, const int* in_sizes, int n_in,
                              void* d_out, int out_size, void* d_ws, size_t ws_size,
                              hipStream_t stream) {
    const float* x = (const float*)d_in[0];
    const float* W = (const float*)d_in[1];
    const float* b = (const float*)d_in[2];
    float* out = (float*)d_out;
    char* ws = (char*)d_ws;

    // workspace layout (bytes):
    unsigned short* WXTH = (unsigned short*)(ws);                              // 8 MB
    unsigned short* WXTL = (unsigned short*)(ws + (size_t)8  * 1024 * 1024);   // 8 MB
    unsigned short* WHT  = (unsigned short*)(ws + (size_t)16 * 1024 * 1024);   // 8 MB
    float*          XZ   = (float*)         (ws + (size_t)24 * 1024 * 1024);   // 128 MB fp32
    int*            FLAGS= (int*)           (ws + (size_t)152 * 1024 * 1024);  // 64 KB (TSEQ*NB)
    unsigned short* HROT = (unsigned short*)(ws + (size_t)152 * 1024 * 1024 + 65536); // 129*128KB
    // optional precomputed A operands (guarded by ws_size):
    unsigned short* XH   = (unsigned short*)(ws + (size_t)170 * 1024 * 1024);  // 16 MB
    unsigned short* XL   = (unsigned short*)(ws + (size_t)186 * 1024 * 1024);  // 16 MB
    const int use_pre = (ws_size >= (size_t)202 * 1024 * 1024) ? 1 : 0;

    // zero FLAGS (64 KB) + HROT slot 0 (128 KB) = 196608 B = 49152 words
    k_init<<<256, 256, 0, stream>>>((uint32_t*)FLAGS, 49152);
    if (use_pre) k_cx<<<2048, 256, 0, stream>>>(x, XH, XL);
    dim3 gtw(64, 32);
    k_tw<<<gtw, 256, 0, stream>>>(W, WXTH, WXTL, WHT);
    dim3 gg(32, 64);   // x: N/128, y: M/128
    k_gemm1<<<gg, 256, 0, stream>>>(x, XH, XL, WXTH, WXTL, XZ, use_pre);
    k_rnn<<<NB, 256, 0, stream>>>(XZ, WHT, b, HROT, FLAGS, out);
}

// Round 11
// 1024.881 us; speedup vs baseline: 1.4629x; 1.0200x over previous
//
#include <hip/hip_runtime.h>
#include <stdint.h>

// Problem: B=64, T=128, F=1024, H=1024. x:[64,128,1024] f32, W:[2048,4096] f32, b:[4096] f32.
// out:[64,128,1024] f32.
#define BATCH 64
#define TSEQ  128
#define FDIM  1024
#define HDIM  1024
#define GDIM  4096              // 4H
#define MROWS 8192              // BATCH*TSEQ
#define NB    128               // persistent blocks in recurrent phase (co-resident on 256 CUs)

typedef short bf16x8 __attribute__((ext_vector_type(8)));   // 8 bf16 in 4 VGPRs
typedef float f32x4  __attribute__((ext_vector_type(4)));

__device__ __forceinline__ unsigned short f2bf(float f) {
    union { float f; uint32_t u; } v; v.f = f;
    uint32_t u = v.u;
    return (unsigned short)((u + 0x7FFFu + ((u >> 16) & 1u)) >> 16);  // RNE
}
__device__ __forceinline__ float bf2f(unsigned short h) {
    union { uint32_t u; float f; } v; v.u = ((uint32_t)h) << 16; return v.f;
}
__device__ __forceinline__ float sigmoidf_(float x) { return 1.f / (1.f + __expf(-x)); }
__device__ __forceinline__ float tanhf_(float x)    { return 2.f / (1.f + __expf(-2.f * x)) - 1.f; }

union SP { short s[8]; int4 v; };
union UU { int4 i; bf16x8 v; };

// L2-bypass 8B store (relaxed agent atomic -> global_store_dwordx2 sc0 sc1, lands at IF).
__device__ __forceinline__ void st64cc(void* p, unsigned long long v) {
    __hip_atomic_store((unsigned long long*)p, v, __ATOMIC_RELAXED, __HIP_MEMORY_SCOPE_AGENT);
}
// L2-bypass 4B store (flag signal).
__device__ __forceinline__ void st32cc(void* p, uint32_t v) {
    __hip_atomic_store((uint32_t*)p, v, __ATOMIC_RELAXED, __HIP_MEMORY_SCOPE_AGENT);
}
// async global->LDS 16B: wave-uniform LDS base + lane*16; global addr per-lane.
__device__ __forceinline__ void gl16(const unsigned short* g, short* l) {
    __builtin_amdgcn_global_load_lds((const __attribute__((address_space(1))) void*)g,
                                     (__attribute__((address_space(3))) void*)l, 16, 0, 0);
}

// ---------------- init: zero flags + h slot 0 ----------------
__global__ void k_init(uint32_t* p, int nwords) {
    int i = blockIdx.x * blockDim.x + threadIdx.x;
    int s = gridDim.x * blockDim.x;
    for (; i < nwords; i += s) p[i] = 0;
}

// ---------------- x fp32 [8192][1024] -> Xh/Xl bf16 hi/lo (one-time) ----------
__global__ __launch_bounds__(256) void k_cx(const float* __restrict__ x,
                                            unsigned short* __restrict__ xh,
                                            unsigned short* __restrict__ xl) {
    const int i = (blockIdx.x * 256 + threadIdx.x) * 16;   // grid 2048 -> covers 8M elems
    float v[16];
    *(float4*)(v)      = *(const float4*)(x + i);
    *(float4*)(v + 4)  = *(const float4*)(x + i + 4);
    *(float4*)(v + 8)  = *(const float4*)(x + i + 8);
    *(float4*)(v + 12) = *(const float4*)(x + i + 12);
    SP h0, h1, l0, l1;
#pragma unroll
    for (int j = 0; j < 8; j++) {
        unsigned short h = f2bf(v[j]);
        h0.s[j] = (short)h; l0.s[j] = (short)f2bf(v[j] - bf2f(h));
        unsigned short g = f2bf(v[8 + j]);
        h1.s[j] = (short)g; l1.s[j] = (short)f2bf(v[8 + j] - bf2f(g));
    }
    *(int4*)(xh + i)     = h0.v;
    *(int4*)(xh + i + 8) = h1.v;
    *(int4*)(xl + i)     = l0.v;
    *(int4*)(xl + i + 8) = l1.v;
}

// ---------------- W fp32 [2048][4096] -> WxT hi/lo bf16 [4096][1024], WhT bf16 [4096][1024] ----
__global__ void k_tw(const float* __restrict__ W,
                     unsigned short* __restrict__ wxth, unsigned short* __restrict__ wxtl,
                     unsigned short* __restrict__ wht) {
    __shared__ float tile[64 * 65];
    const int nb = blockIdx.x;      // 0..63  (n tiles)
    const int kb = blockIdx.y;      // 0..31  (k tiles over 2048)
    const int t  = threadIdx.x;
    const int col = t & 63, rg = t >> 6;
#pragma unroll
    for (int i = 0; i < 16; i++) {
        int row = rg * 16 + i;
        tile[row * 65 + col] = W[(size_t)(kb * 64 + row) * 4096 + nb * 64 + col];
    }
    __syncthreads();
    if (kb < 16) {
        const int kbase = kb * 64;
#pragma unroll
        for (int i = 0; i < 16; i++) {
            int rp = rg * 16 + i;                      // n index within tile
            float v = tile[col * 65 + rp];             // = W[kb*64+col][nb*64+rp]
            unsigned short h = f2bf(v);
            size_t idx = (size_t)(nb * 64 + rp) * 1024 + kbase + col;
            wxth[idx] = h;
            wxtl[idx] = f2bf(v - bf2f(h));
        }
    } else {
        const int kbase = (kb - 16) * 64;
#pragma unroll
        for (int i = 0; i < 16; i++) {
            int rp = rg * 16 + i;
            float v = tile[col * 65 + rp];
            wht[(size_t)(nb * 64 + rp) * 1024 + kbase + col] = f2bf(v);
        }
    }
}

// ---------------- GEMM1 (use_pre path): xz = x @ Wx via global_load_lds staging ----------
// All four operand streams are precomputed bf16 -> staging is a pure copy. Each wave
// stages ONE 8KB buffer (8 x global_load_lds width-16, linear LDS [128][32] shorts).
// ds_read pattern (16 rows x 64B, 4 q-chunks) is bank-uniform (8 lanes/quad) -> no swizzle.
// Same 2-barrier loop as m97's 874-TF structure; 3-MFMA split math unchanged.
__global__ __launch_bounds__(256) void k_gemm1(const unsigned short* __restrict__ Xh,
                                               const unsigned short* __restrict__ Xl,
                                               const unsigned short* __restrict__ WxTh,
                                               const unsigned short* __restrict__ WxTl,
                                               float* __restrict__ xz) {
    __shared__ short Ash[128 * 32];
    __shared__ short Asl[128 * 32];
    __shared__ short Bsh[128 * 32];
    __shared__ short Bsl[128 * 32];
    const int n0 = blockIdx.x * 128;
    const int m0 = blockIdx.y * 128;
    const int t = threadIdx.x;
    const int wave = t >> 6, lane = t & 63;
    const int wm = wave >> 1, wn = wave & 1;
    const int q = lane >> 4, cl = lane & 15;

    // wave -> staging stream
    const unsigned short* gsrc;
    short* lbase;
    if (wave == 0)      { gsrc = Xh   + (size_t)m0 * 1024; lbase = Ash; }
    else if (wave == 1) { gsrc = Xl   + (size_t)m0 * 1024; lbase = Asl; }
    else if (wave == 2) { gsrc = WxTh + (size_t)n0 * 1024; lbase = Bsh; }
    else                { gsrc = WxTl + (size_t)n0 * 1024; lbase = Bsl; }
    // lane's fixed intra-sweep offset: row = lane>>2, col-chunk = (lane&3)*8
    const unsigned short* gl_ptr = gsrc + (size_t)(lane >> 2) * 1024 + (lane & 3) * 8;

    f32x4 acc[4][4];
#pragma unroll
    for (int i = 0; i < 4; i++)
#pragma unroll
        for (int j = 0; j < 4; j++) acc[i][j] = (f32x4){0.f, 0.f, 0.f, 0.f};

    for (int kb = 0; kb < 32; kb++) {
        const int k0 = kb * 32;
        __syncthreads();                    // previous iter's ds_reads complete
#pragma unroll
        for (int s = 0; s < 8; s++)
            gl16(gl_ptr + (size_t)s * 16 * 1024 + k0, lbase + s * 512);
        __syncthreads();                    // vmcnt(0): staged data visible in LDS
        bf16x8 ah[4], al[4], bh[4], bl[4];
#pragma unroll
        for (int i = 0; i < 4; i++) {
            ah[i] = *(const bf16x8*)(Ash + (wm * 64 + i * 16 + cl) * 32 + q * 8);
            al[i] = *(const bf16x8*)(Asl + (wm * 64 + i * 16 + cl) * 32 + q * 8);
        }
#pragma unroll
        for (int j = 0; j < 4; j++) {
            bh[j] = *(const bf16x8*)(Bsh + (wn * 64 + j * 16 + cl) * 32 + q * 8);
            bl[j] = *(const bf16x8*)(Bsl + (wn * 64 + j * 16 + cl) * 32 + q * 8);
        }
#pragma unroll
        for (int i = 0; i < 4; i++)
#pragma unroll
            for (int j = 0; j < 4; j++) {
                acc[i][j] = __builtin_amdgcn_mfma_f32_16x16x32_bf16(ah[i], bh[j], acc[i][j], 0, 0, 0);
                acc[i][j] = __builtin_amdgcn_mfma_f32_16x16x32_bf16(al[i], bh[j], acc[i][j], 0, 0, 0);
                acc[i][j] = __builtin_amdgcn_mfma_f32_16x16x32_bf16(ah[i], bl[j], acc[i][j], 0, 0, 0);
            }
    }
    // epilogue: C/D layout col=lane&15, row=q*4+reg; write fp32
#pragma unroll
    for (int i = 0; i < 4; i++) {
#pragma unroll
        for (int j = 0; j < 4; j++) {
            int gm = m0 + wm * 64 + i * 16 + q * 4;
            int gn = n0 + wn * 64 + j * 16 + cl;
#pragma unroll
            for (int r = 0; r < 4; r++)
                xz[(size_t)(gm + r) * 4096 + gn] = acc[i][j][r];
        }
    }
}

// ---------------- GEMM1 legacy (fallback when workspace lacks Xh/Xl): round-5 version ----
__global__ __launch_bounds__(256) void k_gemm1_legacy(const float* __restrict__ Xf,
                                                      const unsigned short* __restrict__ WxTh,
                                                      const unsigned short* __restrict__ WxTl,
                                                      float* __restrict__ xz) {
    __shared__ short Ash[128 * 40];
    __shared__ short Asl[128 * 40];
    __shared__ short Bsh[128 * 40];
    __shared__ short Bsl[128 * 40];
    const int n0 = blockIdx.x * 128;
    const int m0 = blockIdx.y * 128;
    const int t = threadIdx.x;
    const int wave = t >> 6, lane = t & 63;
    const int wm = wave >> 1, wn = wave & 1;
    const int q = lane >> 4, cl = lane & 15;
    const int row_a = t >> 2;
    const int kc = (t & 3) * 8;

    f32x4 acc[4][4];
#pragma unroll
    for (int i = 0; i < 4; i++)
#pragma unroll
        for (int j = 0; j < 4; j++) acc[i][j] = (f32x4){0.f, 0.f, 0.f, 0.f};

    for (int kb = 0; kb < 32; kb++) {
        const int k0 = kb * 32;
        float va0[8], va1[8];
        {
            const float* p0 = Xf + (size_t)(m0 + row_a) * 1024 + k0 + kc;
            const float* p1 = Xf + (size_t)(m0 + 64 + row_a) * 1024 + k0 + kc;
            *(float4*)(va0)     = *(const float4*)(p0);
            *(float4*)(va0 + 4) = *(const float4*)(p0 + 4);
            *(float4*)(va1)     = *(const float4*)(p1);
            *(float4*)(va1 + 4) = *(const float4*)(p1 + 4);
        }
        int4 bh0 = *(const int4*)(WxTh + (size_t)(n0 + row_a)      * 1024 + k0 + kc);
        int4 bh1 = *(const int4*)(WxTh + (size_t)(n0 + 64 + row_a) * 1024 + k0 + kc);
        int4 bl0 = *(const int4*)(WxTl + (size_t)(n0 + row_a)      * 1024 + k0 + kc);
        int4 bl1 = *(const int4*)(WxTl + (size_t)(n0 + 64 + row_a) * 1024 + k0 + kc);
        __syncthreads();
        {
            SP h0, l0, h1, l1;
#pragma unroll
            for (int i = 0; i < 8; i++) {
                unsigned short h = f2bf(va0[i]);
                h0.s[i] = (short)h; l0.s[i] = (short)f2bf(va0[i] - bf2f(h));
                unsigned short g = f2bf(va1[i]);
                h1.s[i] = (short)g; l1.s[i] = (short)f2bf(va1[i] - bf2f(g));
            }
            *(int4*)(Ash + row_a * 40 + kc)        = h0.v;
            *(int4*)(Asl + row_a * 40 + kc)        = l0.v;
            *(int4*)(Ash + (64 + row_a) * 40 + kc) = h1.v;
            *(int4*)(Asl + (64 + row_a) * 40 + kc) = l1.v;
        }
        *(int4*)(Bsh + row_a * 40 + kc)        = bh0;
        *(int4*)(Bsh + (64 + row_a) * 40 + kc) = bh1;
        *(int4*)(Bsl + row_a * 40 + kc)        = bl0;
        *(int4*)(Bsl + (64 + row_a) * 40 + kc) = bl1;
        __syncthreads();
        bf16x8 ah[4], al[4], bh[4], bl[4];
#pragma unroll
        for (int i = 0; i < 4; i++) {
            ah[i] = *(const bf16x8*)(Ash + (wm * 64 + i * 16 + cl) * 40 + q * 8);
            al[i] = *(const bf16x8*)(Asl + (wm * 64 + i * 16 + cl) * 40 + q * 8);
        }
#pragma unroll
        for (int j = 0; j < 4; j++) {
            bh[j] = *(const bf16x8*)(Bsh + (wn * 64 + j * 16 + cl) * 40 + q * 8);
            bl[j] = *(const bf16x8*)(Bsl + (wn * 64 + j * 16 + cl) * 40 + q * 8);
        }
#pragma unroll
        for (int i = 0; i < 4; i++)
#pragma unroll
            for (int j = 0; j < 4; j++) {
                acc[i][j] = __builtin_amdgcn_mfma_f32_16x16x32_bf16(ah[i], bh[j], acc[i][j], 0, 0, 0);
                acc[i][j] = __builtin_amdgcn_mfma_f32_16x16x32_bf16(al[i], bh[j], acc[i][j], 0, 0, 0);
                acc[i][j] = __builtin_amdgcn_mfma_f32_16x16x32_bf16(ah[i], bl[j], acc[i][j], 0, 0, 0);
            }
    }
#pragma unroll
    for (int i = 0; i < 4; i++) {
#pragma unroll
        for (int j = 0; j < 4; j++) {
            int gm = m0 + wm * 64 + i * 16 + q * 4;
            int gn = n0 + wn * 64 + j * 16 + cl;
#pragma unroll
            for (int r = 0; r < 4; r++)
                xz[(size_t)(gm + r) * 4096 + gn] = acc[i][j][r];
        }
    }
}

// ---------------- persistent recurrent kernel (round-5 form: 750 us, best) ----------------
// NB=128 blocks x 256 thr (4 waves, 1/SIMD). Block owns 8 h-cols -> 32 gate cols
// [i(8) j(8) | f(8) o(8)]. B (Wh slice) entirely in 256 VGPRs.
// h exchange: ROTATING buffer (write-once addresses); producers bypass-store to IF,
// consumers normal cached loads. Distributed write-once flags, full-barrier poll.
__global__ __launch_bounds__(256, 1) void k_rnn(const float* __restrict__ xz,
                                                const unsigned short* __restrict__ WhT,
                                                const float* __restrict__ bias,
                                                unsigned short* hrot,       // 129 x [64][1024] bf16
                                                int* flags,                 // TSEQ x NB ints, write-once
                                                float* __restrict__ out) {
    __shared__ short hs[64 * 8];        // h transpose staging, 1 KB (only LDS left)
    const int t = threadIdx.x;
    const int blk = blockIdx.x;
    // XCD-grouped columns: blocks blk&7==x own cols [x*128, x*128+128)
    const int n0 = (((blk & 7) << 4) | (blk >> 3)) * 8;
    const int wave = t >> 6, lane = t & 63;
    const int q = lane >> 4, cl = lane & 15;
    const int m = wave * 16 + cl;       // A-fragment row (batch)

    const int cc = cl & 7;
    const bool act = (cl < 8);
    float bi = 0.f, bj = 0.f, bfv = 0.f, bo = 0.f;
    if (act) {
        bi  = bias[n0 + cc];
        bj  = bias[1024 + n0 + cc];
        bfv = bias[2048 + n0 + cc];
        bo  = bias[3072 + n0 + cc];
    }

    // B preload: lane (q,cl) holds, for every k-step kb:
    //   B0[kb] = WhT[(cl>>3)*1024   + n0 + (cl&7)][kb*32+q*8 .. +8]   (gates i,j)
    //   B1[kb] = WhT[(2+(cl>>3))*1024 + n0 + (cl&7)][kb*32+q*8 .. +8] (gates f,o)
    bf16x8 B0[32], B1[32];
    {
        const unsigned short* bsrc0 =
            WhT + (size_t)((cl >> 3) * 1024 + n0 + (cl & 7)) * 1024 + q * 8;
        const unsigned short* bsrc1 =
            WhT + (size_t)((2 + (cl >> 3)) * 1024 + n0 + (cl & 7)) * 1024 + q * 8;
#pragma unroll
        for (int kb = 0; kb < 32; kb++) {
            UU u0, u1;
            u0.i = *(const int4*)(bsrc0 + kb * 32);
            u1.i = *(const int4*)(bsrc1 + kb * 32);
            B0[kb] = u0.v;
            B1[kb] = u1.v;
        }
    }

    float c[4] = {0.f, 0.f, 0.f, 0.f};
    // wave-0..3 poll: lane l covers flag words 2l,2l+1; own flag OR'd in locally.
    const unsigned long long selfmask =
        ((t & 63) == (blk >> 1)) ? ((blk & 1) ? (1ULL << 32) : 1ULL) : 0ULL;

    for (int tt = 0; tt < TSEQ; tt++) {
        // prefetch xz for this step (independent of other blocks' h) — ISSUE BEFORE the spin
        float pxi[4], pxj[4], pxf[4], pxo[4];
        if (act) {
#pragma unroll
            for (int r = 0; r < 4; r++) {
                int m2 = wave * 16 + q * 4 + r;
                const float* xp = xz + (size_t)(m2 * 128 + tt) * 4096 + n0 + cc;
                pxi[r] = xp[0];
                pxj[r] = xp[1024];
                pxf[r] = xp[2048];
                pxo[r] = xp[3072];
            }
        }
        __builtin_amdgcn_sched_barrier(0);   // pin: prefetch issued before poll
        if (tt > 0) {
            if (t < 64) {
                const unsigned long long* fp =
                    (const unsigned long long*)flags + (size_t)(tt - 1) * 64 + t;
                unsigned long long v;
                do {
                    v = __hip_atomic_load(fp, __ATOMIC_RELAXED, __HIP_MEMORY_SCOPE_AGENT);
                } while (!__all((v | selfmask) == 0x0000000100000001ULL));
            }
            __syncthreads();
        }
        // burst-load the FULL h row-slice (32 x int4 = 128 VGPRs), all in flight at once.
        // Addresses write-once => normal cached loads safe.
        const char* ab = (const char*)hrot + (size_t)tt * 131072 + (size_t)m * 2048 + q * 16;
        UU aa[32];
#pragma unroll
        for (int kb = 0; kb < 32; kb++) aa[kb].i = *(const int4*)(ab + kb * 64);
        __builtin_amdgcn_sched_barrier(0);   // pin: burst stays a burst

        f32x4 acc0a = (f32x4){0.f, 0.f, 0.f, 0.f};
        f32x4 acc0b = (f32x4){0.f, 0.f, 0.f, 0.f};
        f32x4 acc1a = (f32x4){0.f, 0.f, 0.f, 0.f};
        f32x4 acc1b = (f32x4){0.f, 0.f, 0.f, 0.f};
#pragma unroll
        for (int kb = 0; kb < 32; kb += 2) {
            acc0a = __builtin_amdgcn_mfma_f32_16x16x32_bf16(aa[kb].v,     B0[kb],     acc0a, 0, 0, 0);
            acc1a = __builtin_amdgcn_mfma_f32_16x16x32_bf16(aa[kb].v,     B1[kb],     acc1a, 0, 0, 0);
            acc0b = __builtin_amdgcn_mfma_f32_16x16x32_bf16(aa[kb + 1].v, B0[kb + 1], acc0b, 0, 0, 0);
            acc1b = __builtin_amdgcn_mfma_f32_16x16x32_bf16(aa[kb + 1].v, B1[kb + 1], acc1b, 0, 0, 0);
        }
        f32x4 acc0 = acc0a + acc0b;
        f32x4 acc1 = acc1a + acc1b;
        // gate math: lane (q,cl<8) row-group q*4+r, col cc; zj/zo live in lane^8
        float zi[4], zj[4], zf[4], zo[4];
#pragma unroll
        for (int r = 0; r < 4; r++) {
            float a0 = acc0[r], a1 = acc1[r];
            float a0x = __shfl_xor(a0, 8);
            float a1x = __shfl_xor(a1, 8);
            zi[r] = a0; zj[r] = a0x; zf[r] = a1; zo[r] = a1x;
        }
        float hv4[4];
        if (act) {
#pragma unroll
            for (int r = 0; r < 4; r++) {
                float vi = zi[r] + pxi[r] + bi;
                float vj = zj[r] + pxj[r] + bj;
                float vf = zf[r] + pxf[r] + bfv + 1.0f;    // forget bias
                float vo = zo[r] + pxo[r] + bo;
                float cn = c[r] * sigmoidf_(vf) + sigmoidf_(vi) * tanhf_(vj);
                c[r] = cn;
                float h = tanhf_(cn) * sigmoidf_(vo);
                hv4[r] = h;
                hs[(wave * 16 + q * 4 + r) * 8 + cc] = (short)f2bf(h);
            }
        }
        __syncthreads();   // hs visible to all waves
        if (t < 128) {
            // row = t>>1 (0..63), half = t&1; 8B per store
            unsigned long long hv = *(const unsigned long long*)(hs + (t >> 1) * 8 + (t & 1) * 4);
            st64cc((char*)hrot + (size_t)(tt + 1) * 131072 + (size_t)(t >> 1) * 2048 + n0 * 2 + (t & 1) * 8, hv);
        }
        __syncthreads();   // vmcnt(0): h row-stores ACK'd at IF before signal
        if (t == 0) st32cc(flags + (size_t)tt * NB + blk, 1u);
        // out stores AFTER the signal — off the pre-signal drain critical path
        if (act) {
#pragma unroll
            for (int r = 0; r < 4; r++) {
                int m2 = wave * 16 + q * 4 + r;
                out[(size_t)(m2 * 128 + tt) * 1024 + n0 + cc] = hv4[r];
            }
        }
    }
}

// ---------------- launch ----------------
extern "C" void kernel_launch(void* const* d_in, const int* in_sizes, int n_in,
                              void* d_out, int out_size, void* d_ws, size_t ws_size,
                              hipStream_t stream) {
    const float* x = (const float*)d_in[0];
    const float* W = (const float*)d_in[1];
    const float* b = (const float*)d_in[2];
    float* out = (float*)d_out;
    char* ws = (char*)d_ws;

    // workspace layout (bytes):
    unsigned short* WXTH = (unsigned short*)(ws);                              // 8 MB
    unsigned short* WXTL = (unsigned short*)(ws + (size_t)8  * 1024 * 1024);   // 8 MB
    unsigned short* WHT  = (unsigned short*)(ws + (size_t)16 * 1024 * 1024);   // 8 MB
    float*          XZ   = (float*)         (ws + (size_t)24 * 1024 * 1024);   // 128 MB fp32
    int*            FLAGS= (int*)           (ws + (size_t)152 * 1024 * 1024);  // 64 KB (TSEQ*NB)
    unsigned short* HROT = (unsigned short*)(ws + (size_t)152 * 1024 * 1024 + 65536); // 129*128KB
    // precomputed A operands (guarded by ws_size):
    unsigned short* XH   = (unsigned short*)(ws + (size_t)170 * 1024 * 1024);  // 16 MB
    unsigned short* XL   = (unsigned short*)(ws + (size_t)186 * 1024 * 1024);  // 16 MB
    const int use_pre = (ws_size >= (size_t)202 * 1024 * 1024) ? 1 : 0;

    // zero FLAGS (64 KB) + HROT slot 0 (128 KB) = 196608 B = 49152 words
    k_init<<<256, 256, 0, stream>>>((uint32_t*)FLAGS, 49152);
    dim3 gtw(64, 32);
    k_tw<<<gtw, 256, 0, stream>>>(W, WXTH, WXTL, WHT);
    dim3 gg(32, 64);   // x: N/128, y: M/128
    if (use_pre) {
        k_cx<<<2048, 256, 0, stream>>>(x, XH, XL);
        k_gemm1<<<gg, 256, 0, stream>>>(XH, XL, WXTH, WXTL, XZ);
    } else {
        k_gemm1_legacy<<<gg, 256, 0, stream>>>(x, WXTH, WXTL, XZ);
    }
    k_rnn<<<NB, 256, 0, stream>>>(XZ, WHT, b, HROT, FLAGS, out);
}

// Round 12
// 895.469 us; speedup vs baseline: 1.6743x; 1.1445x over previous
//
#include <hip/hip_runtime.h>
#include <stdint.h>

// Problem: B=64, T=128, F=1024, H=1024. x:[64,128,1024] f32, W:[2048,4096] f32, b:[4096] f32.
// out:[64,128,1024] f32.
#define BATCH 64
#define TSEQ  128
#define FDIM  1024
#define HDIM  1024
#define GDIM  4096              // 4H
#define MROWS 8192              // BATCH*TSEQ
#define NB    128               // rnn blocks (co-resident; dispatched first)
#define GBLK  2048              // gemm blocks (32 n-tiles x 64 timestep-pair tiles)

typedef short bf16x8 __attribute__((ext_vector_type(8)));   // 8 bf16 in 4 VGPRs
typedef float f32x4  __attribute__((ext_vector_type(4)));

__device__ __forceinline__ unsigned short f2bf(float f) {
    union { float f; uint32_t u; } v; v.f = f;
    uint32_t u = v.u;
    return (unsigned short)((u + 0x7FFFu + ((u >> 16) & 1u)) >> 16);  // RNE
}
__device__ __forceinline__ float bf2f(unsigned short h) {
    union { uint32_t u; float f; } v; v.u = ((uint32_t)h) << 16; return v.f;
}
__device__ __forceinline__ float sigmoidf_(float x) { return 1.f / (1.f + __expf(-x)); }
__device__ __forceinline__ float tanhf_(float x)    { return 2.f / (1.f + __expf(-2.f * x)) - 1.f; }

union SP { short s[8]; int4 v; };
union UU { int4 i; bf16x8 v; };

// L2-bypass 8B store (relaxed agent atomic -> global_store_dwordx2 sc0 sc1, lands at IF).
__device__ __forceinline__ void st64cc(void* p, unsigned long long v) {
    __hip_atomic_store((unsigned long long*)p, v, __ATOMIC_RELAXED, __HIP_MEMORY_SCOPE_AGENT);
}
// L2-bypass 4B store.
__device__ __forceinline__ void st32cc(void* p, uint32_t v) {
    __hip_atomic_store((uint32_t*)p, v, __ATOMIC_RELAXED, __HIP_MEMORY_SCOPE_AGENT);
}
// async global->LDS 16B: wave-uniform LDS base + lane*16; global addr per-lane.
__device__ __forceinline__ void gl16(const unsigned short* g, short* l) {
    __builtin_amdgcn_global_load_lds((const __attribute__((address_space(1))) void*)g,
                                     (__attribute__((address_space(3))) void*)l, 16, 0, 0);
}

// ---------------- init: zero flags + gflags + h slot 0 ----------------
__global__ void k_init(uint32_t* p, int nwords) {
    int i = blockIdx.x * blockDim.x + threadIdx.x;
    int s = gridDim.x * blockDim.x;
    for (; i < nwords; i += s) p[i] = 0;
}

// ---------------- x fp32 [8192][1024] -> Xh/Xl bf16 hi/lo (one-time) ----------
__global__ __launch_bounds__(256) void k_cx(const float* __restrict__ x,
                                            unsigned short* __restrict__ xh,
                                            unsigned short* __restrict__ xl) {
    const int i = (blockIdx.x * 256 + threadIdx.x) * 16;   // grid 2048 -> covers 8M elems
    float v[16];
    *(float4*)(v)      = *(const float4*)(x + i);
    *(float4*)(v + 4)  = *(const float4*)(x + i + 4);
    *(float4*)(v + 8)  = *(const float4*)(x + i + 8);
    *(float4*)(v + 12) = *(const float4*)(x + i + 12);
    SP h0, h1, l0, l1;
#pragma unroll
    for (int j = 0; j < 8; j++) {
        unsigned short h = f2bf(v[j]);
        h0.s[j] = (short)h; l0.s[j] = (short)f2bf(v[j] - bf2f(h));
        unsigned short g = f2bf(v[8 + j]);
        h1.s[j] = (short)g; l1.s[j] = (short)f2bf(v[8 + j] - bf2f(g));
    }
    *(int4*)(xh + i)     = h0.v;
    *(int4*)(xh + i + 8) = h1.v;
    *(int4*)(xl + i)     = l0.v;
    *(int4*)(xl + i + 8) = l1.v;
}

// ---------------- W fp32 [2048][4096] -> WxT hi/lo bf16 [4096][1024], WhT bf16 [4096][1024] ----
__global__ void k_tw(const float* __restrict__ W,
                     unsigned short* __restrict__ wxth, unsigned short* __restrict__ wxtl,
                     unsigned short* __restrict__ wht) {
    __shared__ float tile[64 * 65];
    const int nb = blockIdx.x;      // 0..63  (n tiles)
    const int kb = blockIdx.y;      // 0..31  (k tiles over 2048)
    const int t  = threadIdx.x;
    const int col = t & 63, rg = t >> 6;
#pragma unroll
    for (int i = 0; i < 16; i++) {
        int row = rg * 16 + i;
        tile[row * 65 + col] = W[(size_t)(kb * 64 + row) * 4096 + nb * 64 + col];
    }
    __syncthreads();
    if (kb < 16) {
        const int kbase = kb * 64;
#pragma unroll
        for (int i = 0; i < 16; i++) {
            int rp = rg * 16 + i;                      // n index within tile
            float v = tile[col * 65 + rp];             // = W[kb*64+col][nb*64+rp]
            unsigned short h = f2bf(v);
            size_t idx = (size_t)(nb * 64 + rp) * 1024 + kbase + col;
            wxth[idx] = h;
            wxtl[idx] = f2bf(v - bf2f(h));
        }
    } else {
        const int kbase = (kb - 16) * 64;
#pragma unroll
        for (int i = 0; i < 16; i++) {
            int rp = rg * 16 + i;
            float v = tile[col * 65 + rp];
            wht[(size_t)(nb * 64 + rp) * 1024 + kbase + col] = f2bf(v);
        }
    }
}

// ================= FUSED: gemm1 producer blocks + rnn consumer blocks =================
// blocks 0..127: rnn (dispatched first -> co-resident). blocks 128..2175: gemm.
// gemm tile (bx, by): cols [bx*128,+128), rows = all 64 batches x timesteps {2by, 2by+1}
//   (tile row r -> xz/Xh row (r&63)*128 + 2*by + (r>>6); per-lane global addrs make
//   the remap free for global_load_lds staging and the dword epilogue).
// xz handoff uses the verified hrot protocol: write-once addresses, producer L2-BYPASS
//   stores (land at IF; cross-XCD safe without kernel-boundary flush), wave-local
//   vmcnt(0), write-once gflag[by*32+bx]; consumers normal cached loads AFTER flag.
// rnn wave 1 polls gflag[(tt+2)>>1] concurrently with wave 0's h-poll (1-step
//   lookahead keeps the px prefetch position; gemm stays off the critical path).
// Deadlock-free: gemm never waits; gemm retirement frees CUs for any pending block.
__global__ __launch_bounds__(256, 1) void k_fused(
        const unsigned short* __restrict__ Xh, const unsigned short* __restrict__ Xl,
        const unsigned short* __restrict__ WxTh, const unsigned short* __restrict__ WxTl,
        float* __restrict__ xz,
        const unsigned short* __restrict__ WhT, const float* __restrict__ bias,
        unsigned short* hrot,       // 129 x [64][1024] bf16
        int* flags,                 // TSEQ x NB ints, write-once (h readiness)
        int* gflags,                // 64 x 32 ints, write-once (xz tile readiness)
        float* __restrict__ out) {
    __shared__ short Sh[16384];     // gemm staging 32 KB (4 x 128x32 shorts)
    __shared__ short hs[64 * 8];    // rnn h transpose staging, 1 KB
    const int t = threadIdx.x;
    const int wave = t >> 6, lane = t & 63;
    const int q = lane >> 4, cl = lane & 15;

    if (blockIdx.x >= NB) {
        // ---------------- GEMM role ----------------
        const int bid2 = blockIdx.x - NB;
        const int bx = bid2 & 31, by = bid2 >> 5;
        const int n0g = bx * 128;
        const int wm = wave >> 1, wn = wave & 1;
        short* Ash = Sh;
        short* Asl = Sh + 4096;
        short* Bsh = Sh + 8192;
        short* Bsl = Sh + 12288;
        const unsigned short* gA;
        short* lb;
        if (wave == 0)      { gA = Xh; lb = Ash; }
        else if (wave == 1) { gA = Xl; lb = Asl; }
        else if (wave == 2) { gA = WxTh + (size_t)n0g * 1024; lb = Bsh; }
        else                { gA = WxTl + (size_t)n0g * 1024; lb = Bsl; }
        const int kcg = (lane & 3) * 8;
        const int rb = lane >> 2;

        f32x4 acc[4][4];
#pragma unroll
        for (int i = 0; i < 4; i++)
#pragma unroll
            for (int j = 0; j < 4; j++) acc[i][j] = (f32x4){0.f, 0.f, 0.f, 0.f};

        for (int kb = 0; kb < 32; kb++) {
            const int k0 = kb * 32;
            __syncthreads();                 // previous iter's ds_reads complete
#pragma unroll
            for (int s = 0; s < 8; s++) {
                const int r = rb + s * 16;   // tile row 0..127
                size_t grow;
                if (wave < 2) grow = (size_t)((r & 63) * 128 + 2 * by + (r >> 6));
                else          grow = (size_t)r;
                gl16(gA + grow * 1024 + k0 + kcg, lb + s * 512);
            }
            __syncthreads();                 // vmcnt(0): staged data visible
            bf16x8 ah[4], al[4], bh[4], bl[4];
#pragma unroll
            for (int i = 0; i < 4; i++) {
                ah[i] = *(const bf16x8*)(Ash + (wm * 64 + i * 16 + cl) * 32 + q * 8);
                al[i] = *(const bf16x8*)(Asl + (wm * 64 + i * 16 + cl) * 32 + q * 8);
            }
#pragma unroll
            for (int j = 0; j < 4; j++) {
                bh[j] = *(const bf16x8*)(Bsh + (wn * 64 + j * 16 + cl) * 32 + q * 8);
                bl[j] = *(const bf16x8*)(Bsl + (wn * 64 + j * 16 + cl) * 32 + q * 8);
            }
#pragma unroll
            for (int i = 0; i < 4; i++)
#pragma unroll
                for (int j = 0; j < 4; j++) {
                    acc[i][j] = __builtin_amdgcn_mfma_f32_16x16x32_bf16(ah[i], bh[j], acc[i][j], 0, 0, 0);
                    acc[i][j] = __builtin_amdgcn_mfma_f32_16x16x32_bf16(al[i], bh[j], acc[i][j], 0, 0, 0);
                    acc[i][j] = __builtin_amdgcn_mfma_f32_16x16x32_bf16(ah[i], bl[j], acc[i][j], 0, 0, 0);
                }
        }
        // epilogue: L2-bypass dword stores (write-once addresses), then flag
#pragma unroll
        for (int i = 0; i < 4; i++) {
#pragma unroll
            for (int j = 0; j < 4; j++) {
                const int tr = wm * 64 + i * 16 + q * 4;
                const int gn = n0g + wn * 64 + j * 16 + cl;
#pragma unroll
                for (int r2 = 0; r2 < 4; r2++) {
                    const int rr = tr + r2;
                    const size_t grow = (size_t)((rr & 63) * 128 + 2 * by + (rr >> 6));
                    st32cc(xz + grow * 4096 + gn, __float_as_uint(acc[i][j][r2]));
                }
            }
        }
        asm volatile("s_waitcnt vmcnt(0)" ::: "memory");   // wave-local: stores at IF
        __syncthreads();                                   // all waves drained
        if (t == 0) st32cc(gflags + by * 32 + bx, 1u);
        return;
    }

    // ---------------- RNN role (round-5 verified body + gemm gating) ----------------
    const int blk = blockIdx.x;
    // XCD-grouped columns: blocks blk&7==x own cols [x*128, x*128+128)
    const int n0 = (((blk & 7) << 4) | (blk >> 3)) * 8;
    const int m = wave * 16 + cl;       // A-fragment row (batch)

    const int cc = cl & 7;
    const bool act = (cl < 8);
    float bi = 0.f, bj = 0.f, bfv = 0.f, bo = 0.f;
    if (act) {
        bi  = bias[n0 + cc];
        bj  = bias[1024 + n0 + cc];
        bfv = bias[2048 + n0 + cc];
        bo  = bias[3072 + n0 + cc];
    }

    // B preload: lane (q,cl) holds for every k-step kb:
    //   B0[kb] = WhT[(cl>>3)*1024   + n0 + (cl&7)][kb*32+q*8 .. +8]   (gates i,j)
    //   B1[kb] = WhT[(2+(cl>>3))*1024 + n0 + (cl&7)][kb*32+q*8 .. +8] (gates f,o)
    bf16x8 B0[32], B1[32];
    {
        const unsigned short* bsrc0 =
            WhT + (size_t)((cl >> 3) * 1024 + n0 + (cl & 7)) * 1024 + q * 8;
        const unsigned short* bsrc1 =
            WhT + (size_t)((2 + (cl >> 3)) * 1024 + n0 + (cl & 7)) * 1024 + q * 8;
#pragma unroll
        for (int kb = 0; kb < 32; kb++) {
            UU u0, u1;
            u0.i = *(const int4*)(bsrc0 + kb * 32);
            u1.i = *(const int4*)(bsrc1 + kb * 32);
            B0[kb] = u0.v;
            B1[kb] = u1.v;
        }
    }

    float c[4] = {0.f, 0.f, 0.f, 0.f};
    // wave-0 h-poll: lane l covers flag words 2l,2l+1; own flag OR'd in locally.
    const unsigned long long selfmask =
        ((t & 63) == (blk >> 1)) ? ((blk & 1) ? (1ULL << 32) : 1ULL) : 0ULL;

    // prologue: wave 1 waits for gemm tile-pair 0 (covers tt=0,1)
    if (wave == 1) {
        bool ok;
        do {
            unsigned long long v = (lane < 4)
                ? __hip_atomic_load((const unsigned long long*)gflags + lane,
                                    __ATOMIC_RELAXED, __HIP_MEMORY_SCOPE_AGENT)
                : 0x0000000100000001ULL;
            ok = (v == 0x0000000100000001ULL);
        } while (!__all(ok));
    }
    __syncthreads();

    for (int tt = 0; tt < TSEQ; tt++) {
        // prefetch xz for this step (readiness guaranteed by prologue/lookahead)
        float pxi[4], pxj[4], pxf[4], pxo[4];
        if (act) {
#pragma unroll
            for (int r = 0; r < 4; r++) {
                int m2 = wave * 16 + q * 4 + r;
                const float* xp = xz + (size_t)(m2 * 128 + tt) * 4096 + n0 + cc;
                pxi[r] = xp[0];
                pxj[r] = xp[1024];
                pxf[r] = xp[2048];
                pxo[r] = xp[3072];
            }
        }
        __builtin_amdgcn_sched_barrier(0);   // pin: prefetch issued before poll
        if (tt > 0) {
            if (t < 64) {
                const unsigned long long* fp =
                    (const unsigned long long*)flags + (size_t)(tt - 1) * 64 + t;
                unsigned long long v;
                do {
                    v = __hip_atomic_load(fp, __ATOMIC_RELAXED, __HIP_MEMORY_SCOPE_AGENT);
                } while (!__all((v | selfmask) == 0x0000000100000001ULL));
            } else if (wave == 1) {
                // lookahead: confirm gemm tile-pair for steps tt+1/tt+2
                const int byn = (tt + 2) >> 1;
                if (byn < 64) {
                    bool ok;
                    do {
                        unsigned long long v = (lane < 4)
                            ? __hip_atomic_load((const unsigned long long*)gflags + byn * 4 + lane,
                                                __ATOMIC_RELAXED, __HIP_MEMORY_SCOPE_AGENT)
                            : 0x0000000100000001ULL;
                        ok = (v == 0x0000000100000001ULL);
                    } while (!__all(ok));
                }
            }
            __syncthreads();
        }
        // burst-load the FULL h row-slice (32 x int4 = 128 VGPRs), all in flight at once.
        const char* ab = (const char*)hrot + (size_t)tt * 131072 + (size_t)m * 2048 + q * 16;
        UU aa[32];
#pragma unroll
        for (int kb = 0; kb < 32; kb++) aa[kb].i = *(const int4*)(ab + kb * 64);
        __builtin_amdgcn_sched_barrier(0);   // pin: burst stays a burst

        f32x4 acc0a = (f32x4){0.f, 0.f, 0.f, 0.f};
        f32x4 acc0b = (f32x4){0.f, 0.f, 0.f, 0.f};
        f32x4 acc1a = (f32x4){0.f, 0.f, 0.f, 0.f};
        f32x4 acc1b = (f32x4){0.f, 0.f, 0.f, 0.f};
#pragma unroll
        for (int kb = 0; kb < 32; kb += 2) {
            acc0a = __builtin_amdgcn_mfma_f32_16x16x32_bf16(aa[kb].v,     B0[kb],     acc0a, 0, 0, 0);
            acc1a = __builtin_amdgcn_mfma_f32_16x16x32_bf16(aa[kb].v,     B1[kb],     acc1a, 0, 0, 0);
            acc0b = __builtin_amdgcn_mfma_f32_16x16x32_bf16(aa[kb + 1].v, B0[kb + 1], acc0b, 0, 0, 0);
            acc1b = __builtin_amdgcn_mfma_f32_16x16x32_bf16(aa[kb + 1].v, B1[kb + 1], acc1b, 0, 0, 0);
        }
        f32x4 acc0 = acc0a + acc0b;
        f32x4 acc1 = acc1a + acc1b;
        // gate math: lane (q,cl<8) row-group q*4+r, col cc; zj/zo live in lane^8
        float zi[4], zj[4], zf[4], zo[4];
#pragma unroll
        for (int r = 0; r < 4; r++) {
            float a0 = acc0[r], a1 = acc1[r];
            float a0x = __shfl_xor(a0, 8);
            float a1x = __shfl_xor(a1, 8);
            zi[r] = a0; zj[r] = a0x; zf[r] = a1; zo[r] = a1x;
        }
        float hv4[4];
        if (act) {
#pragma unroll
            for (int r = 0; r < 4; r++) {
                float vi = zi[r] + pxi[r] + bi;
                float vj = zj[r] + pxj[r] + bj;
                float vf = zf[r] + pxf[r] + bfv + 1.0f;    // forget bias
                float vo = zo[r] + pxo[r] + bo;
                float cn = c[r] * sigmoidf_(vf) + sigmoidf_(vi) * tanhf_(vj);
                c[r] = cn;
                float h = tanhf_(cn) * sigmoidf_(vo);
                hv4[r] = h;
                hs[(wave * 16 + q * 4 + r) * 8 + cc] = (short)f2bf(h);
            }
        }
        __syncthreads();   // hs visible to all waves
        if (t < 128) {
            // row = t>>1 (0..63), half = t&1; 8B per store
            unsigned long long hv = *(const unsigned long long*)(hs + (t >> 1) * 8 + (t & 1) * 4);
            st64cc((char*)hrot + (size_t)(tt + 1) * 131072 + (size_t)(t >> 1) * 2048 + n0 * 2 + (t & 1) * 8, hv);
        }
        __syncthreads();   // vmcnt(0): h row-stores ACK'd at IF before signal
        if (t == 0) st32cc(flags + (size_t)tt * NB + blk, 1u);
        // out stores AFTER the signal — off the pre-signal drain critical path
        if (act) {
#pragma unroll
            for (int r = 0; r < 4; r++) {
                int m2 = wave * 16 + q * 4 + r;
                out[(size_t)(m2 * 128 + tt) * 1024 + n0 + cc] = hv4[r];
            }
        }
    }
}

// ---------------- fallback pieces (workspace too small for Xh/Xl) ----------------
__global__ __launch_bounds__(256) void k_gemm1_legacy(const float* __restrict__ Xf,
                                                      const unsigned short* __restrict__ WxTh,
                                                      const unsigned short* __restrict__ WxTl,
                                                      float* __restrict__ xz) {
    __shared__ short Ash[128 * 40];
    __shared__ short Asl[128 * 40];
    __shared__ short Bsh[128 * 40];
    __shared__ short Bsl[128 * 40];
    const int n0 = blockIdx.x * 128;
    const int m0 = blockIdx.y * 128;
    const int t = threadIdx.x;
    const int wave = t >> 6, lane = t & 63;
    const int wm = wave >> 1, wn = wave & 1;
    const int q = lane >> 4, cl = lane & 15;
    const int row_a = t >> 2;
    const int kc = (t & 3) * 8;

    f32x4 acc[4][4];
#pragma unroll
    for (int i = 0; i < 4; i++)
#pragma unroll
        for (int j = 0; j < 4; j++) acc[i][j] = (f32x4){0.f, 0.f, 0.f, 0.f};

    for (int kb = 0; kb < 32; kb++) {
        const int k0 = kb * 32;
        float va0[8], va1[8];
        {
            const float* p0 = Xf + (size_t)(m0 + row_a) * 1024 + k0 + kc;
            const float* p1 = Xf + (size_t)(m0 + 64 + row_a) * 1024 + k0 + kc;
            *(float4*)(va0)     = *(const float4*)(p0);
            *(float4*)(va0 + 4) = *(const float4*)(p0 + 4);
            *(float4*)(va1)     = *(const float4*)(p1);
            *(float4*)(va1 + 4) = *(const float4*)(p1 + 4);
        }
        int4 bh0 = *(const int4*)(WxTh + (size_t)(n0 + row_a)      * 1024 + k0 + kc);
        int4 bh1 = *(const int4*)(WxTh + (size_t)(n0 + 64 + row_a) * 1024 + k0 + kc);
        int4 bl0 = *(const int4*)(WxTl + (size_t)(n0 + row_a)      * 1024 + k0 + kc);
        int4 bl1 = *(const int4*)(WxTl + (size_t)(n0 + 64 + row_a) * 1024 + k0 + kc);
        __syncthreads();
        {
            SP h0, l0, h1, l1;
#pragma unroll
            for (int i = 0; i < 8; i++) {
                unsigned short h = f2bf(va0[i]);
                h0.s[i] = (short)h; l0.s[i] = (short)f2bf(va0[i] - bf2f(h));
                unsigned short g = f2bf(va1[i]);
                h1.s[i] = (short)g; l1.s[i] = (short)f2bf(va1[i] - bf2f(g));
            }
            *(int4*)(Ash + row_a * 40 + kc)        = h0.v;
            *(int4*)(Asl + row_a * 40 + kc)        = l0.v;
            *(int4*)(Ash + (64 + row_a) * 40 + kc) = h1.v;
            *(int4*)(Asl + (64 + row_a) * 40 + kc) = l1.v;
        }
        *(int4*)(Bsh + row_a * 40 + kc)        = bh0;
        *(int4*)(Bsh + (64 + row_a) * 40 + kc) = bh1;
        *(int4*)(Bsl + row_a * 40 + kc)        = bl0;
        *(int4*)(Bsl + (64 + row_a) * 40 + kc) = bl1;
        __syncthreads();
        bf16x8 ah[4], al[4], bh[4], bl[4];
#pragma unroll
        for (int i = 0; i < 4; i++) {
            ah[i] = *(const bf16x8*)(Ash + (wm * 64 + i * 16 + cl) * 40 + q * 8);
            al[i] = *(const bf16x8*)(Asl + (wm * 64 + i * 16 + cl) * 40 + q * 8);
        }
#pragma unroll
        for (int j = 0; j < 4; j++) {
            bh[j] = *(const bf16x8*)(Bsh + (wn * 64 + j * 16 + cl) * 40 + q * 8);
            bl[j] = *(const bf16x8*)(Bsl + (wn * 64 + j * 16 + cl) * 40 + q * 8);
        }
#pragma unroll
        for (int i = 0; i < 4; i++)
#pragma unroll
            for (int j = 0; j < 4; j++) {
                acc[i][j] = __builtin_amdgcn_mfma_f32_16x16x32_bf16(ah[i], bh[j], acc[i][j], 0, 0, 0);
                acc[i][j] = __builtin_amdgcn_mfma_f32_16x16x32_bf16(al[i], bh[j], acc[i][j], 0, 0, 0);
                acc[i][j] = __builtin_amdgcn_mfma_f32_16x16x32_bf16(ah[i], bl[j], acc[i][j], 0, 0, 0);
            }
    }
#pragma unroll
    for (int i = 0; i < 4; i++) {
#pragma unroll
        for (int j = 0; j < 4; j++) {
            int gm = m0 + wm * 64 + i * 16 + q * 4;
            int gn = n0 + wn * 64 + j * 16 + cl;
#pragma unroll
            for (int r = 0; r < 4; r++)
                xz[(size_t)(gm + r) * 4096 + gn] = acc[i][j][r];
        }
    }
}

__global__ __launch_bounds__(256, 1) void k_rnn(const float* __restrict__ xz,
                                                const unsigned short* __restrict__ WhT,
                                                const float* __restrict__ bias,
                                                unsigned short* hrot,
                                                int* flags,
                                                float* __restrict__ out) {
    __shared__ short hs[64 * 8];
    const int t = threadIdx.x;
    const int blk = blockIdx.x;
    const int n0 = (((blk & 7) << 4) | (blk >> 3)) * 8;
    const int wave = t >> 6, lane = t & 63;
    const int q = lane >> 4, cl = lane & 15;
    const int m = wave * 16 + cl;

    const int cc = cl & 7;
    const bool act = (cl < 8);
    float bi = 0.f, bj = 0.f, bfv = 0.f, bo = 0.f;
    if (act) {
        bi  = bias[n0 + cc];
        bj  = bias[1024 + n0 + cc];
        bfv = bias[2048 + n0 + cc];
        bo  = bias[3072 + n0 + cc];
    }
    bf16x8 B0[32], B1[32];
    {
        const unsigned short* bsrc0 =
            WhT + (size_t)((cl >> 3) * 1024 + n0 + (cl & 7)) * 1024 + q * 8;
        const unsigned short* bsrc1 =
            WhT + (size_t)((2 + (cl >> 3)) * 1024 + n0 + (cl & 7)) * 1024 + q * 8;
#pragma unroll
        for (int kb = 0; kb < 32; kb++) {
            UU u0, u1;
            u0.i = *(const int4*)(bsrc0 + kb * 32);
            u1.i = *(const int4*)(bsrc1 + kb * 32);
            B0[kb] = u0.v;
            B1[kb] = u1.v;
        }
    }
    float c[4] = {0.f, 0.f, 0.f, 0.f};
    const unsigned long long selfmask =
        ((t & 63) == (blk >> 1)) ? ((blk & 1) ? (1ULL << 32) : 1ULL) : 0ULL;

    for (int tt = 0; tt < TSEQ; tt++) {
        float pxi[4], pxj[4], pxf[4], pxo[4];
        if (act) {
#pragma unroll
            for (int r = 0; r < 4; r++) {
                int m2 = wave * 16 + q * 4 + r;
                const float* xp = xz + (size_t)(m2 * 128 + tt) * 4096 + n0 + cc;
                pxi[r] = xp[0];
                pxj[r] = xp[1024];
                pxf[r] = xp[2048];
                pxo[r] = xp[3072];
            }
        }
        __builtin_amdgcn_sched_barrier(0);
        if (tt > 0) {
            if (t < 64) {
                const unsigned long long* fp =
                    (const unsigned long long*)flags + (size_t)(tt - 1) * 64 + t;
                unsigned long long v;
                do {
                    v = __hip_atomic_load(fp, __ATOMIC_RELAXED, __HIP_MEMORY_SCOPE_AGENT);
                } while (!__all((v | selfmask) == 0x0000000100000001ULL));
            }
            __syncthreads();
        }
        const char* ab = (const char*)hrot + (size_t)tt * 131072 + (size_t)m * 2048 + q * 16;
        UU aa[32];
#pragma unroll
        for (int kb = 0; kb < 32; kb++) aa[kb].i = *(const int4*)(ab + kb * 64);
        __builtin_amdgcn_sched_barrier(0);

        f32x4 acc0a = (f32x4){0.f, 0.f, 0.f, 0.f};
        f32x4 acc0b = (f32x4){0.f, 0.f, 0.f, 0.f};
        f32x4 acc1a = (f32x4){0.f, 0.f, 0.f, 0.f};
        f32x4 acc1b = (f32x4){0.f, 0.f, 0.f, 0.f};
#pragma unroll
        for (int kb = 0; kb < 32; kb += 2) {
            acc0a = __builtin_amdgcn_mfma_f32_16x16x32_bf16(aa[kb].v,     B0[kb],     acc0a, 0, 0, 0);
            acc1a = __builtin_amdgcn_mfma_f32_16x16x32_bf16(aa[kb].v,     B1[kb],     acc1a, 0, 0, 0);
            acc0b = __builtin_amdgcn_mfma_f32_16x16x32_bf16(aa[kb + 1].v, B0[kb + 1], acc0b, 0, 0, 0);
            acc1b = __builtin_amdgcn_mfma_f32_16x16x32_bf16(aa[kb + 1].v, B1[kb + 1], acc1b, 0, 0, 0);
        }
        f32x4 acc0 = acc0a + acc0b;
        f32x4 acc1 = acc1a + acc1b;
        float zi[4], zj[4], zf[4], zo[4];
#pragma unroll
        for (int r = 0; r < 4; r++) {
            float a0 = acc0[r], a1 = acc1[r];
            float a0x = __shfl_xor(a0, 8);
            float a1x = __shfl_xor(a1, 8);
            zi[r] = a0; zj[r] = a0x; zf[r] = a1; zo[r] = a1x;
        }
        float hv4[4];
        if (act) {
#pragma unroll
            for (int r = 0; r < 4; r++) {
                float vi = zi[r] + pxi[r] + bi;
                float vj = zj[r] + pxj[r] + bj;
                float vf = zf[r] + pxf[r] + bfv + 1.0f;
                float vo = zo[r] + pxo[r] + bo;
                float cn = c[r] * sigmoidf_(vf) + sigmoidf_(vi) * tanhf_(vj);
                c[r] = cn;
                float h = tanhf_(cn) * sigmoidf_(vo);
                hv4[r] = h;
                hs[(wave * 16 + q * 4 + r) * 8 + cc] = (short)f2bf(h);
            }
        }
        __syncthreads();
        if (t < 128) {
            unsigned long long hv = *(const unsigned long long*)(hs + (t >> 1) * 8 + (t & 1) * 4);
            st64cc((char*)hrot + (size_t)(tt + 1) * 131072 + (size_t)(t >> 1) * 2048 + n0 * 2 + (t & 1) * 8, hv);
        }
        __syncthreads();
        if (t == 0) st32cc(flags + (size_t)tt * NB + blk, 1u);
        if (act) {
#pragma unroll
            for (int r = 0; r < 4; r++) {
                int m2 = wave * 16 + q * 4 + r;
                out[(size_t)(m2 * 128 + tt) * 1024 + n0 + cc] = hv4[r];
            }
        }
    }
}

// ---------------- launch ----------------
extern "C" void kernel_launch(void* const* d_in, const int* in_sizes, int n_in,
                              void* d_out, int out_size, void* d_ws, size_t ws_size,
                              hipStream_t stream) {
    const float* x = (const float*)d_in[0];
    const float* W = (const float*)d_in[1];
    const float* b = (const float*)d_in[2];
    float* out = (float*)d_out;
    char* ws = (char*)d_ws;

    // workspace layout (bytes):
    unsigned short* WXTH = (unsigned short*)(ws);                              // 8 MB
    unsigned short* WXTL = (unsigned short*)(ws + (size_t)8  * 1024 * 1024);   // 8 MB
    unsigned short* WHT  = (unsigned short*)(ws + (size_t)16 * 1024 * 1024);   // 8 MB
    float*          XZ   = (float*)         (ws + (size_t)24 * 1024 * 1024);   // 128 MB fp32
    int*            FLAGS= (int*)           (ws + (size_t)152 * 1024 * 1024);  // 64 KB (TSEQ*NB)
    int*            GFLAGS=(int*)           (ws + (size_t)152 * 1024 * 1024 + 65536);  // 8 KB
    unsigned short* HROT = (unsigned short*)(ws + (size_t)152 * 1024 * 1024 + 131072); // 129*128KB
    unsigned short* XH   = (unsigned short*)(ws + (size_t)170 * 1024 * 1024);  // 16 MB
    unsigned short* XL   = (unsigned short*)(ws + (size_t)186 * 1024 * 1024);  // 16 MB
    const int use_pre = (ws_size >= (size_t)202 * 1024 * 1024) ? 1 : 0;

    // zero FLAGS(64K) + GFLAGS(8K) + pad + HROT slot 0 (128K) = 256 KB = 65536 words
    k_init<<<256, 256, 0, stream>>>((uint32_t*)FLAGS, 65536);
    dim3 gtw(64, 32);
    k_tw<<<gtw, 256, 0, stream>>>(W, WXTH, WXTL, WHT);
    if (use_pre) {
        k_cx<<<2048, 256, 0, stream>>>(x, XH, XL);
        k_fused<<<NB + GBLK, 256, 0, stream>>>(XH, XL, WXTH, WXTL, XZ, WHT, b,
                                               HROT, FLAGS, GFLAGS, out);
    } else {
        dim3 gg(32, 64);
        k_gemm1_legacy<<<gg, 256, 0, stream>>>(x, WXTH, WXTL, XZ);
        k_rnn<<<NB, 256, 0, stream>>>(XZ, WHT, b, HROT, FLAGS, out);
    }
}

// Round 13
// 891.398 us; speedup vs baseline: 1.6819x; 1.0046x over previous
//
#include <hip/hip_runtime.h>
#include <stdint.h>

// Problem: B=64, T=128, F=1024, H=1024. x:[64,128,1024] f32, W:[2048,4096] f32, b:[4096] f32.
// out:[64,128,1024] f32.
#define BATCH 64
#define TSEQ  128
#define FDIM  1024
#define HDIM  1024
#define GDIM  4096              // 4H
#define MROWS 8192              // BATCH*TSEQ
#define NB    128               // rnn blocks (co-resident; dispatched first)
#define GBLK  2048              // gemm blocks (32 n-tiles x 64 timestep-pair tiles)

typedef short bf16x8 __attribute__((ext_vector_type(8)));   // 8 bf16 in 4 VGPRs
typedef float f32x4  __attribute__((ext_vector_type(4)));

__device__ __forceinline__ unsigned short f2bf(float f) {
    union { float f; uint32_t u; } v; v.f = f;
    uint32_t u = v.u;
    return (unsigned short)((u + 0x7FFFu + ((u >> 16) & 1u)) >> 16);  // RNE
}
__device__ __forceinline__ float bf2f(unsigned short h) {
    union { uint32_t u; float f; } v; v.u = ((uint32_t)h) << 16; return v.f;
}
__device__ __forceinline__ float sigmoidf_(float x) { return 1.f / (1.f + __expf(-x)); }
__device__ __forceinline__ float tanhf_(float x)    { return 2.f / (1.f + __expf(-2.f * x)) - 1.f; }

union SP { short s[8]; int4 v; };
union UU { int4 i; bf16x8 v; };

// L2-bypass 8B store (relaxed agent atomic -> global_store_dwordx2 sc0 sc1, lands at IF).
__device__ __forceinline__ void st64cc(void* p, unsigned long long v) {
    __hip_atomic_store((unsigned long long*)p, v, __ATOMIC_RELAXED, __HIP_MEMORY_SCOPE_AGENT);
}
// L2-bypass 4B store.
__device__ __forceinline__ void st32cc(void* p, uint32_t v) {
    __hip_atomic_store((uint32_t*)p, v, __ATOMIC_RELAXED, __HIP_MEMORY_SCOPE_AGENT);
}
// async global->LDS 16B: wave-uniform LDS base + lane*16; global addr per-lane.
__device__ __forceinline__ void gl16(const unsigned short* g, short* l) {
    __builtin_amdgcn_global_load_lds((const __attribute__((address_space(1))) void*)g,
                                     (__attribute__((address_space(3))) void*)l, 16, 0, 0);
}

// ================= MERGED PROLOGUE: init + cx + tw in ONE launch =================
// blocks 0..31: zero flags/gflags/hrot-slot0 (65536 words). blocks 32..2079: x->Xh/Xl.
// blocks 2080..4127: W transpose/split. All roles independent; replaces 3 serialized
// launches (~75 us incl gaps) with one (~20-25 us of parallel memory work).
__global__ __launch_bounds__(256) void k_pre(const float* __restrict__ x,
                                             const float* __restrict__ W,
                                             uint32_t* __restrict__ zp,
                                             unsigned short* __restrict__ xh,
                                             unsigned short* __restrict__ xl,
                                             unsigned short* __restrict__ wxth,
                                             unsigned short* __restrict__ wxtl,
                                             unsigned short* __restrict__ wht,
                                             int use_pre) {
    __shared__ float tile[64 * 65];
    const int bid = blockIdx.x;
    const int t = threadIdx.x;
    if (bid < 32) {
        // ---- init role: zero 65536 words (FLAGS 64K + GFLAGS 8K + pad + HROT slot0 128K)
        for (int i = bid * 256 + t; i < 65536; i += 32 * 256) zp[i] = 0;
        return;
    }
    if (bid < 32 + 2048) {
        // ---- cx role: x fp32 [8192][1024] -> Xh/Xl bf16 hi/lo
        if (!use_pre) return;
        const int i = ((bid - 32) * 256 + t) * 16;
        float v[16];
        *(float4*)(v)      = *(const float4*)(x + i);
        *(float4*)(v + 4)  = *(const float4*)(x + i + 4);
        *(float4*)(v + 8)  = *(const float4*)(x + i + 8);
        *(float4*)(v + 12) = *(const float4*)(x + i + 12);
        SP h0, h1, l0, l1;
#pragma unroll
        for (int j = 0; j < 8; j++) {
            unsigned short h = f2bf(v[j]);
            h0.s[j] = (short)h; l0.s[j] = (short)f2bf(v[j] - bf2f(h));
            unsigned short g = f2bf(v[8 + j]);
            h1.s[j] = (short)g; l1.s[j] = (short)f2bf(v[8 + j] - bf2f(g));
        }
        *(int4*)(xh + i)     = h0.v;
        *(int4*)(xh + i + 8) = h1.v;
        *(int4*)(xl + i)     = l0.v;
        *(int4*)(xl + i + 8) = l1.v;
        return;
    }
    // ---- tw role: W fp32 [2048][4096] -> WxT hi/lo bf16 [4096][1024], WhT bf16
    const int idx = bid - 2080;
    const int nb = idx & 63;        // 0..63  (n tiles)
    const int kb = idx >> 6;        // 0..31  (k tiles over 2048)
    const int col = t & 63, rg = t >> 6;
#pragma unroll
    for (int i = 0; i < 16; i++) {
        int row = rg * 16 + i;
        tile[row * 65 + col] = W[(size_t)(kb * 64 + row) * 4096 + nb * 64 + col];
    }
    __syncthreads();
    if (kb < 16) {
        const int kbase = kb * 64;
#pragma unroll
        for (int i = 0; i < 16; i++) {
            int rp = rg * 16 + i;                      // n index within tile
            float v = tile[col * 65 + rp];             // = W[kb*64+col][nb*64+rp]
            unsigned short h = f2bf(v);
            size_t idx2 = (size_t)(nb * 64 + rp) * 1024 + kbase + col;
            wxth[idx2] = h;
            wxtl[idx2] = f2bf(v - bf2f(h));
        }
    } else {
        const int kbase = (kb - 16) * 64;
#pragma unroll
        for (int i = 0; i < 16; i++) {
            int rp = rg * 16 + i;
            float v = tile[col * 65 + rp];
            wht[(size_t)(nb * 64 + rp) * 1024 + kbase + col] = f2bf(v);
        }
    }
}

// ================= FUSED: gemm1 producer blocks + rnn consumer blocks =================
// blocks 0..127: rnn (dispatched first -> co-resident). blocks 128..2175: gemm.
// gemm tile (bx, by): cols [bx*128,+128), rows = all 64 batches x timesteps {2by, 2by+1}
//   (tile row r -> xz/Xh row (r&63)*128 + 2*by + (r>>6); per-lane global addrs make
//   the remap free for global_load_lds staging and the dword epilogue).
// xz handoff uses the verified hrot protocol: write-once addresses, producer L2-BYPASS
//   stores (land at IF; cross-XCD safe without kernel-boundary flush), wave-local
//   vmcnt(0), write-once gflag[by*32+bx]; consumers normal cached loads AFTER flag.
// rnn wave 1 polls gflag[(tt+2)>>1] concurrently with wave 0's h-poll (1-step
//   lookahead keeps the px prefetch position; gemm stays off the critical path).
// Deadlock-free: gemm never waits; gemm retirement frees CUs for any pending block.
__global__ __launch_bounds__(256, 1) void k_fused(
        const unsigned short* __restrict__ Xh, const unsigned short* __restrict__ Xl,
        const unsigned short* __restrict__ WxTh, const unsigned short* __restrict__ WxTl,
        float* __restrict__ xz,
        const unsigned short* __restrict__ WhT, const float* __restrict__ bias,
        unsigned short* hrot,       // 129 x [64][1024] bf16
        int* flags,                 // TSEQ x NB ints, write-once (h readiness)
        int* gflags,                // 64 x 32 ints, write-once (xz tile readiness)
        float* __restrict__ out) {
    __shared__ short Sh[16384];     // gemm staging 32 KB (4 x 128x32 shorts)
    __shared__ short hs[64 * 8];    // rnn h transpose staging, 1 KB
    const int t = threadIdx.x;
    const int wave = t >> 6, lane = t & 63;
    const int q = lane >> 4, cl = lane & 15;

    if (blockIdx.x >= NB) {
        // ---------------- GEMM role ----------------
        const int bid2 = blockIdx.x - NB;
        const int bx = bid2 & 31, by = bid2 >> 5;
        const int n0g = bx * 128;
        const int wm = wave >> 1, wn = wave & 1;
        short* Ash = Sh;
        short* Asl = Sh + 4096;
        short* Bsh = Sh + 8192;
        short* Bsl = Sh + 12288;
        const unsigned short* gA;
        short* lb;
        if (wave == 0)      { gA = Xh; lb = Ash; }
        else if (wave == 1) { gA = Xl; lb = Asl; }
        else if (wave == 2) { gA = WxTh + (size_t)n0g * 1024; lb = Bsh; }
        else                { gA = WxTl + (size_t)n0g * 1024; lb = Bsl; }
        const int kcg = (lane & 3) * 8;
        const int rb = lane >> 2;

        f32x4 acc[4][4];
#pragma unroll
        for (int i = 0; i < 4; i++)
#pragma unroll
            for (int j = 0; j < 4; j++) acc[i][j] = (f32x4){0.f, 0.f, 0.f, 0.f};

        for (int kb = 0; kb < 32; kb++) {
            const int k0 = kb * 32;
            __syncthreads();                 // previous iter's ds_reads complete
#pragma unroll
            for (int s = 0; s < 8; s++) {
                const int r = rb + s * 16;   // tile row 0..127
                size_t grow;
                if (wave < 2) grow = (size_t)((r & 63) * 128 + 2 * by + (r >> 6));
                else          grow = (size_t)r;
                gl16(gA + grow * 1024 + k0 + kcg, lb + s * 512);
            }
            __syncthreads();                 // vmcnt(0): staged data visible
            bf16x8 ah[4], al[4], bh[4], bl[4];
#pragma unroll
            for (int i = 0; i < 4; i++) {
                ah[i] = *(const bf16x8*)(Ash + (wm * 64 + i * 16 + cl) * 32 + q * 8);
                al[i] = *(const bf16x8*)(Asl + (wm * 64 + i * 16 + cl) * 32 + q * 8);
            }
#pragma unroll
            for (int j = 0; j < 4; j++) {
                bh[j] = *(const bf16x8*)(Bsh + (wn * 64 + j * 16 + cl) * 32 + q * 8);
                bl[j] = *(const bf16x8*)(Bsl + (wn * 64 + j * 16 + cl) * 32 + q * 8);
            }
#pragma unroll
            for (int i = 0; i < 4; i++)
#pragma unroll
                for (int j = 0; j < 4; j++) {
                    acc[i][j] = __builtin_amdgcn_mfma_f32_16x16x32_bf16(ah[i], bh[j], acc[i][j], 0, 0, 0);
                    acc[i][j] = __builtin_amdgcn_mfma_f32_16x16x32_bf16(al[i], bh[j], acc[i][j], 0, 0, 0);
                    acc[i][j] = __builtin_amdgcn_mfma_f32_16x16x32_bf16(ah[i], bl[j], acc[i][j], 0, 0, 0);
                }
        }
        // epilogue: L2-bypass dword stores (write-once addresses), then flag
#pragma unroll
        for (int i = 0; i < 4; i++) {
#pragma unroll
            for (int j = 0; j < 4; j++) {
                const int tr = wm * 64 + i * 16 + q * 4;
                const int gn = n0g + wn * 64 + j * 16 + cl;
#pragma unroll
                for (int r2 = 0; r2 < 4; r2++) {
                    const int rr = tr + r2;
                    const size_t grow = (size_t)((rr & 63) * 128 + 2 * by + (rr >> 6));
                    st32cc(xz + grow * 4096 + gn, __float_as_uint(acc[i][j][r2]));
                }
            }
        }
        asm volatile("s_waitcnt vmcnt(0)" ::: "memory");   // wave-local: stores at IF
        __syncthreads();                                   // all waves drained
        if (t == 0) st32cc(gflags + by * 32 + bx, 1u);
        return;
    }

    // ---------------- RNN role (round-5 verified body + gemm gating) ----------------
    const int blk = blockIdx.x;
    // XCD-grouped columns: blocks blk&7==x own cols [x*128, x*128+128)
    const int n0 = (((blk & 7) << 4) | (blk >> 3)) * 8;
    const int m = wave * 16 + cl;       // A-fragment row (batch)

    const int cc = cl & 7;
    const bool act = (cl < 8);
    float bi = 0.f, bj = 0.f, bfv = 0.f, bo = 0.f;
    if (act) {
        bi  = bias[n0 + cc];
        bj  = bias[1024 + n0 + cc];
        bfv = bias[2048 + n0 + cc];
        bo  = bias[3072 + n0 + cc];
    }

    // B preload: lane (q,cl) holds for every k-step kb:
    //   B0[kb] = WhT[(cl>>3)*1024   + n0 + (cl&7)][kb*32+q*8 .. +8]   (gates i,j)
    //   B1[kb] = WhT[(2+(cl>>3))*1024 + n0 + (cl&7)][kb*32+q*8 .. +8] (gates f,o)
    bf16x8 B0[32], B1[32];
    {
        const unsigned short* bsrc0 =
            WhT + (size_t)((cl >> 3) * 1024 + n0 + (cl & 7)) * 1024 + q * 8;
        const unsigned short* bsrc1 =
            WhT + (size_t)((2 + (cl >> 3)) * 1024 + n0 + (cl & 7)) * 1024 + q * 8;
#pragma unroll
        for (int kb = 0; kb < 32; kb++) {
            UU u0, u1;
            u0.i = *(const int4*)(bsrc0 + kb * 32);
            u1.i = *(const int4*)(bsrc1 + kb * 32);
            B0[kb] = u0.v;
            B1[kb] = u1.v;
        }
    }

    float c[4] = {0.f, 0.f, 0.f, 0.f};
    // wave-0 h-poll: lane l covers flag words 2l,2l+1; own flag OR'd in locally.
    const unsigned long long selfmask =
        ((t & 63) == (blk >> 1)) ? ((blk & 1) ? (1ULL << 32) : 1ULL) : 0ULL;

    // prologue: wave 1 waits for gemm tile-pair 0 (covers tt=0,1)
    if (wave == 1) {
        bool ok;
        do {
            unsigned long long v = (lane < 4)
                ? __hip_atomic_load((const unsigned long long*)gflags + lane,
                                    __ATOMIC_RELAXED, __HIP_MEMORY_SCOPE_AGENT)
                : 0x0000000100000001ULL;
            ok = (v == 0x0000000100000001ULL);
        } while (!__all(ok));
    }
    __syncthreads();

    for (int tt = 0; tt < TSEQ; tt++) {
        // prefetch xz for this step (readiness guaranteed by prologue/lookahead)
        float pxi[4], pxj[4], pxf[4], pxo[4];
        if (act) {
#pragma unroll
            for (int r = 0; r < 4; r++) {
                int m2 = wave * 16 + q * 4 + r;
                const float* xp = xz + (size_t)(m2 * 128 + tt) * 4096 + n0 + cc;
                pxi[r] = xp[0];
                pxj[r] = xp[1024];
                pxf[r] = xp[2048];
                pxo[r] = xp[3072];
            }
        }
        __builtin_amdgcn_sched_barrier(0);   // pin: prefetch issued before poll
        if (tt > 0) {
            if (t < 64) {
                const unsigned long long* fp =
                    (const unsigned long long*)flags + (size_t)(tt - 1) * 64 + t;
                unsigned long long v;
                do {
                    v = __hip_atomic_load(fp, __ATOMIC_RELAXED, __HIP_MEMORY_SCOPE_AGENT);
                } while (!__all((v | selfmask) == 0x0000000100000001ULL));
            } else if (wave == 1) {
                // lookahead: confirm gemm tile-pair for steps tt+1/tt+2
                const int byn = (tt + 2) >> 1;
                if (byn < 64) {
                    bool ok;
                    do {
                        unsigned long long v = (lane < 4)
                            ? __hip_atomic_load((const unsigned long long*)gflags + byn * 4 + lane,
                                                __ATOMIC_RELAXED, __HIP_MEMORY_SCOPE_AGENT)
                            : 0x0000000100000001ULL;
                        ok = (v == 0x0000000100000001ULL);
                    } while (!__all(ok));
                }
            }
            __syncthreads();
        }
        // burst-load the FULL h row-slice (32 x int4 = 128 VGPRs), all in flight at once.
        const char* ab = (const char*)hrot + (size_t)tt * 131072 + (size_t)m * 2048 + q * 16;
        UU aa[32];
#pragma unroll
        for (int kb = 0; kb < 32; kb++) aa[kb].i = *(const int4*)(ab + kb * 64);
        __builtin_amdgcn_sched_barrier(0);   // pin: burst stays a burst

        f32x4 acc0a = (f32x4){0.f, 0.f, 0.f, 0.f};
        f32x4 acc0b = (f32x4){0.f, 0.f, 0.f, 0.f};
        f32x4 acc1a = (f32x4){0.f, 0.f, 0.f, 0.f};
        f32x4 acc1b = (f32x4){0.f, 0.f, 0.f, 0.f};
#pragma unroll
        for (int kb = 0; kb < 32; kb += 2) {
            acc0a = __builtin_amdgcn_mfma_f32_16x16x32_bf16(aa[kb].v,     B0[kb],     acc0a, 0, 0, 0);
            acc1a = __builtin_amdgcn_mfma_f32_16x16x32_bf16(aa[kb].v,     B1[kb],     acc1a, 0, 0, 0);
            acc0b = __builtin_amdgcn_mfma_f32_16x16x32_bf16(aa[kb + 1].v, B0[kb + 1], acc0b, 0, 0, 0);
            acc1b = __builtin_amdgcn_mfma_f32_16x16x32_bf16(aa[kb + 1].v, B1[kb + 1], acc1b, 0, 0, 0);
        }
        f32x4 acc0 = acc0a + acc0b;
        f32x4 acc1 = acc1a + acc1b;
        // gate math: lane (q,cl<8) row-group q*4+r, col cc; zj/zo live in lane^8
        float zi[4], zj[4], zf[4], zo[4];
#pragma unroll
        for (int r = 0; r < 4; r++) {
            float a0 = acc0[r], a1 = acc1[r];
            float a0x = __shfl_xor(a0, 8);
            float a1x = __shfl_xor(a1, 8);
            zi[r] = a0; zj[r] = a0x; zf[r] = a1; zo[r] = a1x;
        }
        float hv4[4];
        if (act) {
#pragma unroll
            for (int r = 0; r < 4; r++) {
                float vi = zi[r] + pxi[r] + bi;
                float vj = zj[r] + pxj[r] + bj;
                float vf = zf[r] + pxf[r] + bfv + 1.0f;    // forget bias
                float vo = zo[r] + pxo[r] + bo;
                float cn = c[r] * sigmoidf_(vf) + sigmoidf_(vi) * tanhf_(vj);
                c[r] = cn;
                float h = tanhf_(cn) * sigmoidf_(vo);
                hv4[r] = h;
                hs[(wave * 16 + q * 4 + r) * 8 + cc] = (short)f2bf(h);
            }
        }
        __syncthreads();   // hs visible to all waves
        if (t < 128) {
            // row = t>>1 (0..63), half = t&1; 8B per store
            unsigned long long hv = *(const unsigned long long*)(hs + (t >> 1) * 8 + (t & 1) * 4);
            st64cc((char*)hrot + (size_t)(tt + 1) * 131072 + (size_t)(t >> 1) * 2048 + n0 * 2 + (t & 1) * 8, hv);
        }
        __syncthreads();   // vmcnt(0): h row-stores ACK'd at IF before signal
        if (t == 0) st32cc(flags + (size_t)tt * NB + blk, 1u);
        // out stores AFTER the signal — off the pre-signal drain critical path
        if (act) {
#pragma unroll
            for (int r = 0; r < 4; r++) {
                int m2 = wave * 16 + q * 4 + r;
                out[(size_t)(m2 * 128 + tt) * 1024 + n0 + cc] = hv4[r];
            }
        }
    }
}

// ---------------- fallback pieces (workspace too small for Xh/Xl) ----------------
__global__ __launch_bounds__(256) void k_gemm1_legacy(const float* __restrict__ Xf,
                                                      const unsigned short* __restrict__ WxTh,
                                                      const unsigned short* __restrict__ WxTl,
                                                      float* __restrict__ xz) {
    __shared__ short Ash[128 * 40];
    __shared__ short Asl[128 * 40];
    __shared__ short Bsh[128 * 40];
    __shared__ short Bsl[128 * 40];
    const int n0 = blockIdx.x * 128;
    const int m0 = blockIdx.y * 128;
    const int t = threadIdx.x;
    const int wave = t >> 6, lane = t & 63;
    const int wm = wave >> 1, wn = wave & 1;
    const int q = lane >> 4, cl = lane & 15;
    const int row_a = t >> 2;
    const int kc = (t & 3) * 8;

    f32x4 acc[4][4];
#pragma unroll
    for (int i = 0; i < 4; i++)
#pragma unroll
        for (int j = 0; j < 4; j++) acc[i][j] = (f32x4){0.f, 0.f, 0.f, 0.f};

    for (int kb = 0; kb < 32; kb++) {
        const int k0 = kb * 32;
        float va0[8], va1[8];
        {
            const float* p0 = Xf + (size_t)(m0 + row_a) * 1024 + k0 + kc;
            const float* p1 = Xf + (size_t)(m0 + 64 + row_a) * 1024 + k0 + kc;
            *(float4*)(va0)     = *(const float4*)(p0);
            *(float4*)(va0 + 4) = *(const float4*)(p0 + 4);
            *(float4*)(va1)     = *(const float4*)(p1);
            *(float4*)(va1 + 4) = *(const float4*)(p1 + 4);
        }
        int4 bh0 = *(const int4*)(WxTh + (size_t)(n0 + row_a)      * 1024 + k0 + kc);
        int4 bh1 = *(const int4*)(WxTh + (size_t)(n0 + 64 + row_a) * 1024 + k0 + kc);
        int4 bl0 = *(const int4*)(WxTl + (size_t)(n0 + row_a)      * 1024 + k0 + kc);
        int4 bl1 = *(const int4*)(WxTl + (size_t)(n0 + 64 + row_a) * 1024 + k0 + kc);
        __syncthreads();
        {
            SP h0, l0, h1, l1;
#pragma unroll
            for (int i = 0; i < 8; i++) {
                unsigned short h = f2bf(va0[i]);
                h0.s[i] = (short)h; l0.s[i] = (short)f2bf(va0[i] - bf2f(h));
                unsigned short g = f2bf(va1[i]);
                h1.s[i] = (short)g; l1.s[i] = (short)f2bf(va1[i] - bf2f(g));
            }
            *(int4*)(Ash + row_a * 40 + kc)        = h0.v;
            *(int4*)(Asl + row_a * 40 + kc)        = l0.v;
            *(int4*)(Ash + (64 + row_a) * 40 + kc) = h1.v;
            *(int4*)(Asl + (64 + row_a) * 40 + kc) = l1.v;
        }
        *(int4*)(Bsh + row_a * 40 + kc)        = bh0;
        *(int4*)(Bsh + (64 + row_a) * 40 + kc) = bh1;
        *(int4*)(Bsl + row_a * 40 + kc)        = bl0;
        *(int4*)(Bsl + (64 + row_a) * 40 + kc) = bl1;
        __syncthreads();
        bf16x8 ah[4], al[4], bh[4], bl[4];
#pragma unroll
        for (int i = 0; i < 4; i++) {
            ah[i] = *(const bf16x8*)(Ash + (wm * 64 + i * 16 + cl) * 40 + q * 8);
            al[i] = *(const bf16x8*)(Asl + (wm * 64 + i * 16 + cl) * 40 + q * 8);
        }
#pragma unroll
        for (int j = 0; j < 4; j++) {
            bh[j] = *(const bf16x8*)(Bsh + (wn * 64 + j * 16 + cl) * 40 + q * 8);
            bl[j] = *(const bf16x8*)(Bsl + (wn * 64 + j * 16 + cl) * 40 + q * 8);
        }
#pragma unroll
        for (int i = 0; i < 4; i++)
#pragma unroll
            for (int j = 0; j < 4; j++) {
                acc[i][j] = __builtin_amdgcn_mfma_f32_16x16x32_bf16(ah[i], bh[j], acc[i][j], 0, 0, 0);
                acc[i][j] = __builtin_amdgcn_mfma_f32_16x16x32_bf16(al[i], bh[j], acc[i][j], 0, 0, 0);
                acc[i][j] = __builtin_amdgcn_mfma_f32_16x16x32_bf16(ah[i], bl[j], acc[i][j], 0, 0, 0);
            }
    }
#pragma unroll
    for (int i = 0; i < 4; i++) {
#pragma unroll
        for (int j = 0; j < 4; j++) {
            int gm = m0 + wm * 64 + i * 16 + q * 4;
            int gn = n0 + wn * 64 + j * 16 + cl;
#pragma unroll
            for (int r = 0; r < 4; r++)
                xz[(size_t)(gm + r) * 4096 + gn] = acc[i][j][r];
        }
    }
}

__global__ __launch_bounds__(256, 1) void k_rnn(const float* __restrict__ xz,
                                                const unsigned short* __restrict__ WhT,
                                                const float* __restrict__ bias,
                                                unsigned short* hrot,
                                                int* flags,
                                                float* __restrict__ out) {
    __shared__ short hs[64 * 8];
    const int t = threadIdx.x;
    const int blk = blockIdx.x;
    const int n0 = (((blk & 7) << 4) | (blk >> 3)) * 8;
    const int wave = t >> 6, lane = t & 63;
    const int q = lane >> 4, cl = lane & 15;
    const int m = wave * 16 + cl;

    const int cc = cl & 7;
    const bool act = (cl < 8);
    float bi = 0.f, bj = 0.f, bfv = 0.f, bo = 0.f;
    if (act) {
        bi  = bias[n0 + cc];
        bj  = bias[1024 + n0 + cc];
        bfv = bias[2048 + n0 + cc];
        bo  = bias[3072 + n0 + cc];
    }
    bf16x8 B0[32], B1[32];
    {
        const unsigned short* bsrc0 =
            WhT + (size_t)((cl >> 3) * 1024 + n0 + (cl & 7)) * 1024 + q * 8;
        const unsigned short* bsrc1 =
            WhT + (size_t)((2 + (cl >> 3)) * 1024 + n0 + (cl & 7)) * 1024 + q * 8;
#pragma unroll
        for (int kb = 0; kb < 32; kb++) {
            UU u0, u1;
            u0.i = *(const int4*)(bsrc0 + kb * 32);
            u1.i = *(const int4*)(bsrc1 + kb * 32);
            B0[kb] = u0.v;
            B1[kb] = u1.v;
        }
    }
    float c[4] = {0.f, 0.f, 0.f, 0.f};
    const unsigned long long selfmask =
        ((t & 63) == (blk >> 1)) ? ((blk & 1) ? (1ULL << 32) : 1ULL) : 0ULL;

    for (int tt = 0; tt < TSEQ; tt++) {
        float pxi[4], pxj[4], pxf[4], pxo[4];
        if (act) {
#pragma unroll
            for (int r = 0; r < 4; r++) {
                int m2 = wave * 16 + q * 4 + r;
                const float* xp = xz + (size_t)(m2 * 128 + tt) * 4096 + n0 + cc;
                pxi[r] = xp[0];
                pxj[r] = xp[1024];
                pxf[r] = xp[2048];
                pxo[r] = xp[3072];
            }
        }
        __builtin_amdgcn_sched_barrier(0);
        if (tt > 0) {
            if (t < 64) {
                const unsigned long long* fp =
                    (const unsigned long long*)flags + (size_t)(tt - 1) * 64 + t;
                unsigned long long v;
                do {
                    v = __hip_atomic_load(fp, __ATOMIC_RELAXED, __HIP_MEMORY_SCOPE_AGENT);
                } while (!__all((v | selfmask) == 0x0000000100000001ULL));
            }
            __syncthreads();
        }
        const char* ab = (const char*)hrot + (size_t)tt * 131072 + (size_t)m * 2048 + q * 16;
        UU aa[32];
#pragma unroll
        for (int kb = 0; kb < 32; kb++) aa[kb].i = *(const int4*)(ab + kb * 64);
        __builtin_amdgcn_sched_barrier(0);

        f32x4 acc0a = (f32x4){0.f, 0.f, 0.f, 0.f};
        f32x4 acc0b = (f32x4){0.f, 0.f, 0.f, 0.f};
        f32x4 acc1a = (f32x4){0.f, 0.f, 0.f, 0.f};
        f32x4 acc1b = (f32x4){0.f, 0.f, 0.f, 0.f};
#pragma unroll
        for (int kb = 0; kb < 32; kb += 2) {
            acc0a = __builtin_amdgcn_mfma_f32_16x16x32_bf16(aa[kb].v,     B0[kb],     acc0a, 0, 0, 0);
            acc1a = __builtin_amdgcn_mfma_f32_16x16x32_bf16(aa[kb].v,     B1[kb],     acc1a, 0, 0, 0);
            acc0b = __builtin_amdgcn_mfma_f32_16x16x32_bf16(aa[kb + 1].v, B0[kb + 1], acc0b, 0, 0, 0);
            acc1b = __builtin_amdgcn_mfma_f32_16x16x32_bf16(aa[kb + 1].v, B1[kb + 1], acc1b, 0, 0, 0);
        }
        f32x4 acc0 = acc0a + acc0b;
        f32x4 acc1 = acc1a + acc1b;
        float zi[4], zj[4], zf[4], zo[4];
#pragma unroll
        for (int r = 0; r < 4; r++) {
            float a0 = acc0[r], a1 = acc1[r];
            float a0x = __shfl_xor(a0, 8);
            float a1x = __shfl_xor(a1, 8);
            zi[r] = a0; zj[r] = a0x; zf[r] = a1; zo[r] = a1x;
        }
        float hv4[4];
        if (act) {
#pragma unroll
            for (int r = 0; r < 4; r++) {
                float vi = zi[r] + pxi[r] + bi;
                float vj = zj[r] + pxj[r] + bj;
                float vf = zf[r] + pxf[r] + bfv + 1.0f;
                float vo = zo[r] + pxo[r] + bo;
                float cn = c[r] * sigmoidf_(vf) + sigmoidf_(vi) * tanhf_(vj);
                c[r] = cn;
                float h = tanhf_(cn) * sigmoidf_(vo);
                hv4[r] = h;
                hs[(wave * 16 + q * 4 + r) * 8 + cc] = (short)f2bf(h);
            }
        }
        __syncthreads();
        if (t < 128) {
            unsigned long long hv = *(const unsigned long long*)(hs + (t >> 1) * 8 + (t & 1) * 4);
            st64cc((char*)hrot + (size_t)(tt + 1) * 131072 + (size_t)(t >> 1) * 2048 + n0 * 2 + (t & 1) * 8, hv);
        }
        __syncthreads();
        if (t == 0) st32cc(flags + (size_t)tt * NB + blk, 1u);
        if (act) {
#pragma unroll
            for (int r = 0; r < 4; r++) {
                int m2 = wave * 16 + q * 4 + r;
                out[(size_t)(m2 * 128 + tt) * 1024 + n0 + cc] = hv4[r];
            }
        }
    }
}

// ---------------- launch ----------------
extern "C" void kernel_launch(void* const* d_in, const int* in_sizes, int n_in,
                              void* d_out, int out_size, void* d_ws, size_t ws_size,
                              hipStream_t stream) {
    const float* x = (const float*)d_in[0];
    const float* W = (const float*)d_in[1];
    const float* b = (const float*)d_in[2];
    float* out = (float*)d_out;
    char* ws = (char*)d_ws;

    // workspace layout (bytes):
    unsigned short* WXTH = (unsigned short*)(ws);                              // 8 MB
    unsigned short* WXTL = (unsigned short*)(ws + (size_t)8  * 1024 * 1024);   // 8 MB
    unsigned short* WHT  = (unsigned short*)(ws + (size_t)16 * 1024 * 1024);   // 8 MB
    float*          XZ   = (float*)         (ws + (size_t)24 * 1024 * 1024);   // 128 MB fp32
    int*            FLAGS= (int*)           (ws + (size_t)152 * 1024 * 1024);  // 64 KB (TSEQ*NB)
    int*            GFLAGS=(int*)           (ws + (size_t)152 * 1024 * 1024 + 65536);  // 8 KB
    unsigned short* HROT = (unsigned short*)(ws + (size_t)152 * 1024 * 1024 + 131072); // 129*128KB
    unsigned short* XH   = (unsigned short*)(ws + (size_t)170 * 1024 * 1024);  // 16 MB
    unsigned short* XL   = (unsigned short*)(ws + (size_t)186 * 1024 * 1024);  // 16 MB
    const int use_pre = (ws_size >= (size_t)202 * 1024 * 1024) ? 1 : 0;

    // merged prologue: init (32 blocks) + cx (2048) + tw (2048) in one launch
    k_pre<<<4128, 256, 0, stream>>>(x, W, (uint32_t*)FLAGS, XH, XL, WXTH, WXTL, WHT, use_pre);
    if (use_pre) {
        k_fused<<<NB + GBLK, 256, 0, stream>>>(XH, XL, WXTH, WXTL, XZ, WHT, b,
                                               HROT, FLAGS, GFLAGS, out);
    } else {
        dim3 gg(32, 64);
        k_gemm1_legacy<<<gg, 256, 0, stream>>>(x, WXTH, WXTL, XZ);
        k_rnn<<<NB, 256, 0, stream>>>(XZ, WHT, b, HROT, FLAGS, out);
    }
}